// Round 5
// baseline (1197.828 us; speedup 1.0000x reference)
//
#include <hip/hip_runtime.h>
#include <hip/hip_cooperative_groups.h>
#include <math.h>

namespace cg = cooperative_groups;

#define N_NODES 16384
#define N_EDGES 262144
#define HDIM    128
#define NG50    50
#define NLAYER  6
#define NGRAPH  16
#define TROWS   1025
#define RMAXF   4.34f
#define WPL     16384   // ushorts per packed weight plane (128*128)

__device__ __forceinline__ float ssp_f(float x){
  return (x > 20.0f ? x : log1pf(__expf(x))) - 0.6931471805599453f;
}
__device__ __forceinline__ void fma4(float4& c, float a, const float4 b){
  c.x = fmaf(a,b.x,c.x); c.y = fmaf(a,b.y,c.y); c.z = fmaf(a,b.z,c.z); c.w = fmaf(a,b.w,c.w);
}
// bf16 helpers (RNE)
__device__ __forceinline__ unsigned short f2bf(float x){
  unsigned u = __float_as_uint(x);
  u += 0x7FFF + ((u>>16)&1);
  return (unsigned short)(u>>16);
}
__device__ __forceinline__ float bf2f(unsigned short u){
  return __uint_as_float(((unsigned)u)<<16);
}

// MFMA fragment types
typedef __attribute__((ext_vector_type(8))) short bf16x8;
typedef __attribute__((ext_vector_type(4))) float f32x4;
// LDS XOR swizzle for fp32 [16][128] tiles (512 B rows): involution on 16B
// granules; route EVERY 16B half of a 32B fragment through swzf (R1 lesson).
__device__ __forceinline__ int swzf(int lin){ return lin ^ (((lin>>9)&7)<<4); }

// hi/lo bf16 split of 8 fp32 values (Dekker-style: lo = bf16(x - hi))
__device__ __forceinline__ void split8(const float4 v0, const float4 v1, bf16x8& hi, bf16x8& lo){
  float x[8] = {v0.x,v0.y,v0.z,v0.w,v1.x,v1.y,v1.z,v1.w};
  #pragma unroll
  for (int i=0;i<8;++i){
    unsigned short h = f2bf(x[i]);
    hi[i] = (short)h;
    lo[i] = (short)f2bf(x[i] - bf2f(h));
  }
}

// ================= K1: init_h || tab+pack || hist || wpack =================
#define B_INIT  2048
#define B_TAB   1536  // NLAYER * 256 (4 packed rows per block, 5 computed)
#define B_HIST  1024
#define B_WPACK 144
#define K1_GRID (B_INIT + B_TAB + B_HIST + B_WPACK)

__global__ __launch_bounds__(256) void k_setup1(
    const int* __restrict__ z, const float* __restrict__ emb, float* __restrict__ h,
    const float* __restrict__ w1, const float* __restrict__ b1,
    const float* __restrict__ w2, const float* __restrict__ b2, ushort4* __restrict__ tabp,
    const int* __restrict__ ei, int* __restrict__ cursor,
    const float* __restrict__ cf_w2, const float* __restrict__ lin_w,
    const float* __restrict__ cf_w1, ushort* __restrict__ wp)
{
  __shared__ float ea[5][52];
  __shared__ float sT5[5][HDIM];
  __shared__ float part5[2][5][HDIM];
  __shared__ float fin5[5][HDIM];
  const int b = blockIdx.x;
  const int tid = threadIdx.x;

  if (b < B_INIT){
    // ---- h = emb[z] ----
    int t = b*256 + tid;
    int n = t >> 5, q = t & 31;
    ((float4*)h)[t] = ((const float4*)emb)[(z[n]<<5) + q];
    return;
  }
  if (b < B_INIT + B_TAB){
    // ---- filter table rows i0..i0+4 (row i0+4 recomputed, bit-identical),
    //      pack 4 bf16 lerp-pair rows directly (k_pack folded in) ----
    int bb = b - B_INIT;
    int l  = bb >> 8;
    int i0 = (bb & 255)*4;
    int j    = tid & 127;
    int half = tid >> 7;
    const float* w1l = w1 + (size_t)l*NG50*HDIM;
    const float* w2l = w2 + (size_t)l*HDIM*HDIM;
    const float STEP = RMAXF/1024.0f;
    const float GS   = 10.0f/49.0f;
    const float GC   = -0.5f/(GS*GS);
    if (tid < 5*NG50){
      int rr = tid / NG50, k = tid - rr*NG50;
      int ri = i0 + rr;                     // max 1020+4 = 1024 <= TROWS-1
      float d = ri*STEP - k*GS;
      ea[rr][k] = __expf(GC*d*d);
    }
    __syncthreads();
    {
      float acc[5] = {0,0,0,0,0};
      int kb = half*25;
      for (int k=0;k<25;++k){
        float wv = w1l[(kb+k)*HDIM + j];
        #pragma unroll
        for (int r=0;r<5;++r) acc[r] = fmaf(ea[r][kb+k], wv, acc[r]);
      }
      #pragma unroll
      for (int r=0;r<5;++r) part5[half][r][j] = acc[r];
    }
    __syncthreads();
    {
      float b1v = b1[(size_t)l*HDIM + j];
      #pragma unroll
      for (int rr=0;rr<3;++rr){
        int r = half*3 + rr;
        if (r < 5) sT5[r][j] = ssp_f(part5[0][r][j] + part5[1][r][j] + b1v);
      }
    }
    __syncthreads();
    {
      float o[5] = {0,0,0,0,0};
      int kb = half*64;
      #pragma unroll 4
      for (int k=0;k<64;++k){
        float wv = w2l[(kb+k)*HDIM + j];
        #pragma unroll
        for (int r=0;r<5;++r) o[r] = fmaf(sT5[r][kb+k], wv, o[r]);
      }
      #pragma unroll
      for (int r=0;r<5;++r) part5[half][r][j] = o[r];
    }
    __syncthreads();
    {
      float b2v = b2[(size_t)l*HDIM + j];
      #pragma unroll
      for (int rr=0;rr<3;++rr){
        int r = half*3 + rr;
        if (r < 5){
          int ri = i0 + r;
          float rv = ri*STEP;
          float C = 0.5f*(cosf(rv*0.31415926535897931f) + 1.0f);
          fin5[r][j] = (part5[0][r][j] + part5[1][r][j] + b2v)*C;
        }
      }
    }
    __syncthreads();
    {
      int r  = tid >> 6, ln = tid & 63;
      int ri = i0 + r;                      // <= 1023
      ushort4 p;
      p.x = f2bf(fin5[r][ln*2]);   p.y = f2bf(fin5[r][ln*2+1]);
      p.z = f2bf(fin5[r+1][ln*2]); p.w = f2bf(fin5[r+1][ln*2+1]);
      tabp[((size_t)l*1024 + ri)*64 + ln] = p;
    }
    return;
  }
  if (b < B_INIT + B_TAB + B_HIST){
    // ---- edge histogram ----
    int e = (b - (B_INIT + B_TAB))*256 + tid;
    if (e < N_EDGES) atomicAdd(&cursor[ei[N_EDGES + e]], 1);
    return;
  }
  {
    // ---- weight pack, hi+lo planes ----
    int bb  = b - (B_INIT + B_TAB + B_HIST);   // 0..143 = 18 mats x 8 parts
    int mat = bb >> 3;
    int s   = (bb & 7)*256 + tid;
    const float* M = (mat < 6)  ? cf_w2 + (size_t)mat*HDIM*HDIM
                   : (mat < 12) ? lin_w + (size_t)(mat-6)*HDIM*HDIM
                                : cf_w1 + (size_t)(mat-12)*HDIM*HDIM;
    int ct = s >> 8, ks = (s >> 6) & 3, l = s & 63;
    int col = ct*16 + (l & 15);
    int r0  = ks*32 + (l >> 4)*8;
    ushort oh[8], ol[8];
    #pragma unroll
    for (int i=0;i<8;++i){
      float w = M[(size_t)(r0+i)*HDIM + col];
      oh[i] = f2bf(w);
      ol[i] = f2bf(w - bf2f(oh[i]));
    }
    ushort* dh = wp + (size_t)(2*mat)*WPL + (size_t)s*8;
    ushort* dl = dh + WPL;
    *(ushort4*)(dh+0) = make_ushort4(oh[0],oh[1],oh[2],oh[3]);
    *(ushort4*)(dh+4) = make_ushort4(oh[4],oh[5],oh[6],oh[7]);
    *(ushort4*)(dl+0) = make_ushort4(ol[0],ol[1],ol[2],ol[3]);
    *(ushort4*)(dl+4) = make_ushort4(ol[4],ol[5],ol[6],ol[7]);
  }
}

// ================= K2: CSR scan (single block) =================
__global__ __launch_bounds__(1024) void k_scan(int* __restrict__ cursor, int* __restrict__ rowptr){
  __shared__ int sbuf[1024];
  int t = threadIdx.x;
  int base = t*16;
  int d[16]; int s = 0;
  #pragma unroll
  for (int i=0;i<16;++i){ d[i] = cursor[base+i]; s += d[i]; }
  sbuf[t] = s; __syncthreads();
  for (int off=1; off<1024; off<<=1){
    int v = sbuf[t];
    int add = (t >= off) ? sbuf[t-off] : 0;
    __syncthreads();
    sbuf[t] = v + add;
    __syncthreads();
  }
  int run = (t==0) ? 0 : sbuf[t-1];
  #pragma unroll
  for (int i=0;i<16;++i){ rowptr[base+i] = run; cursor[base+i] = run; run += d[i]; }
  if (t==1023) rowptr[N_NODES] = run;
}

// ================= K3: fill (blocks 0..1023) || gemm_xh (1024..2047) ==========
#define FR 16
__global__ __launch_bounds__(256,4) void k_fill_xh(
    const int* __restrict__ ei, const float* __restrict__ pos,
    int* __restrict__ cursor, int* __restrict__ srcl, float* __restrict__ tl,
    const float* __restrict__ A, const float* __restrict__ B, ushort4* __restrict__ Cb)
{
  __shared__ float Bs[32*HDIM];
  const int tid = threadIdx.x;
  if (blockIdx.x < 1024){
    int e = blockIdx.x*256 + tid;
    if (e < N_EDGES){
      int a = ei[e];
      int c = ei[N_EDGES + e];
      float dx = pos[3*a+0] - pos[3*c+0];
      float dy = pos[3*a+1] - pos[3*c+1];
      float dz = pos[3*a+2] - pos[3*c+2];
      dx -= rintf(dx*0.2f)*5.0f;
      dy -= rintf(dy*0.2f)*5.0f;
      dz -= rintf(dz*0.2f)*5.0f;
      float r = sqrtf(fmaf(dx,dx,fmaf(dy,dy,dz*dz)));
      int slot = atomicAdd(&cursor[c], 1);
      srcl[slot] = a;
      tl[slot]   = r * (1024.0f/RMAXF);
    }
    return;
  }
  // xh(bf16) = h @ cf_w1[0]
  int m0 = (blockIdx.x - 1024)*FR;
  int tc = tid & 31, tr = tid >> 5;
  int j0 = tc*4;
  int lr0 = tr*2, lr1 = tr*2+1;
  float4 acc0 = make_float4(0,0,0,0), acc1 = acc0;
  const float* A0 = A + (size_t)(m0 + lr0)*HDIM;
  const float* A1 = A + (size_t)(m0 + lr1)*HDIM;
  for (int kc=0; kc<HDIM; kc+=32){
    __syncthreads();
    {
      const float4* src = (const float4*)(B + kc*HDIM);
      float4* dst = (float4*)Bs;
      #pragma unroll
      for (int i=0;i<4;++i) dst[tid + i*256] = src[tid + i*256];
    }
    __syncthreads();
    #pragma unroll
    for (int kk=0; kk<32; kk+=4){
      float4 b0 = *(const float4*)(Bs + (kk+0)*HDIM + j0);
      float4 b1 = *(const float4*)(Bs + (kk+1)*HDIM + j0);
      float4 b2 = *(const float4*)(Bs + (kk+2)*HDIM + j0);
      float4 b3 = *(const float4*)(Bs + (kk+3)*HDIM + j0);
      float4 a0 = *(const float4*)(A0 + kc + kk);
      float4 a1 = *(const float4*)(A1 + kc + kk);
      fma4(acc0,a0.x,b0); fma4(acc0,a0.y,b1); fma4(acc0,a0.z,b2); fma4(acc0,a0.w,b3);
      fma4(acc1,a1.x,b0); fma4(acc1,a1.y,b1); fma4(acc1,a1.z,b2); fma4(acc1,a1.w,b3);
    }
  }
  ushort4 o;
  o.x=f2bf(acc0.x); o.y=f2bf(acc0.y); o.z=f2bf(acc0.z); o.w=f2bf(acc0.w);
  Cb[(size_t)(m0 + lr0)*32 + tc] = o;
  o.x=f2bf(acc1.x); o.y=f2bf(acc1.y); o.z=f2bf(acc1.z); o.w=f2bf(acc1.w);
  Cb[(size_t)(m0 + lr1)*32 + tc] = o;
}

// ================= cooperative mega-kernel: 6 layers + out MLP + readout =====
__device__ __forceinline__ void gemm_hl(const ushort* plane, size_t wfo,
    const bf16x8* ah, const bf16x8* al, f32x4* acc){
  #pragma unroll
  for (int ks=0;ks<4;++ks){
    #pragma unroll
    for (int c=0;c<2;++c){
      const ushort* p = plane + wfo + (size_t)(c*4+ks)*512;
      bf16x8 wh = *(const bf16x8*)p;
      bf16x8 wl = *(const bf16x8*)(p + WPL);
      acc[c] = __builtin_amdgcn_mfma_f32_16x16x32_bf16(ah[ks], wh, acc[c], 0,0,0);
      acc[c] = __builtin_amdgcn_mfma_f32_16x16x32_bf16(al[ks], wh, acc[c], 0,0,0);
      acc[c] = __builtin_amdgcn_mfma_f32_16x16x32_bf16(ah[ks], wl, acc[c], 0,0,0);
    }
  }
}

__global__ __launch_bounds__(256,4) void k_mega(
    const int* __restrict__ rowptr, const int* __restrict__ srcl, const float* __restrict__ tl,
    const ushort4* __restrict__ tabp_all, ushort* __restrict__ xhb0, ushort* __restrict__ xhb1,
    const ushort* __restrict__ wpk, const float* __restrict__ cf_b2, const float* __restrict__ lin_b,
    float* __restrict__ Hio,
    const float* __restrict__ ow1, const float* __restrict__ ob1,
    const float* __restrict__ ow2, const float* __restrict__ ob2,
    const int* __restrict__ batch, float* __restrict__ nodeval, float* __restrict__ out)
{
  cg::grid_group grid = cg::this_grid();
  __shared__ alignas(16) float Sa[16*HDIM];   // agg, then h'
  __shared__ alignas(16) float St[16*HDIM];   // t
  __shared__ float sred[4];
  const int tid  = threadIdx.x;
  const int wv   = tid >> 6, lane = tid & 63;
  const int m    = lane & 15, g = lane >> 4;
  const int colA = wv*32 + m;
  const int colB = colA + 16;
  const size_t wfo = (size_t)(wv*8*64 + lane)*8;
  const f32x4 vzero = {0.f,0.f,0.f,0.f};

  for (int l=0; l<NLAYER; ++l){
    const bool last = (l == NLAYER-1);
    const ushort*  w2p  = wpk + (size_t)(2*l)*WPL;
    const ushort*  wlp  = wpk + (size_t)(2*(6+l))*WPL;
    const ushort*  w1p  = wpk + (size_t)(2*(13+l))*WPL;
    const ushort4* tabL = tabp_all + (size_t)l*1024*64;
    const ushort2* xcur = (const ushort2*)((l & 1) ? xhb1 : xhb0);
    ushort*        xnxt = (l & 1) ? xhb0 : xhb1;
    const float*   B2   = cf_b2 + (size_t)l*HDIM;
    const float*   BL   = lin_b + (size_t)l*HDIM;

    for (int tile = blockIdx.x; tile < N_NODES/16; tile += gridDim.x){
      const int m0 = tile*16;

      // ===== phase 1: aggregate 4 nodes per wave into swizzled LDS =====
      {
        const ushort4* tabl = tabL + lane;
        const ushort2* xh2  = xcur + lane;
        for (int i=0;i<4;++i){
          int c = m0 + wv*4 + i;
          int beg = rowptr[c], end = rowptr[c+1];
          float ax = 0.f, ay = 0.f;
          for (int k0 = beg; k0 < end; k0 += 64){
            int rem = end - k0;
            int cnt = rem < 64 ? rem : 64;
            int   s_l = 0; float t_l = 0.f;
            if (lane < cnt){ s_l = srcl[k0+lane]; t_l = tl[k0+lane]; }
            int j = 0;
            for (; j+3 < cnt; j += 4){
              int   r0 = __shfl(s_l, j,   64);
              float t0 = __shfl(t_l, j,   64);
              int   r1 = __shfl(s_l, j+1, 64);
              float t1 = __shfl(t_l, j+1, 64);
              int   r2 = __shfl(s_l, j+2, 64);
              float t2 = __shfl(t_l, j+2, 64);
              int   r3 = __shfl(s_l, j+3, 64);
              float t3 = __shfl(t_l, j+3, 64);
              int i00 = (int)t0; if (i00 > 1023) i00 = 1023;
              int i01 = (int)t1; if (i01 > 1023) i01 = 1023;
              int i02 = (int)t2; if (i02 > 1023) i02 = 1023;
              int i03 = (int)t3; if (i03 > 1023) i03 = 1023;
              float f0 = t0 - (float)i00;
              float f1 = t1 - (float)i01;
              float f2 = t2 - (float)i02;
              float f3 = t3 - (float)i03;
              ushort4 p0 = tabl[(size_t)i00*64];
              ushort4 p1 = tabl[(size_t)i01*64];
              ushort4 p2 = tabl[(size_t)i02*64];
              ushort4 p3 = tabl[(size_t)i03*64];
              ushort2 x0 = xh2[(size_t)r0*64];
              ushort2 x1 = xh2[(size_t)r1*64];
              ushort2 x2 = xh2[(size_t)r2*64];
              ushort2 x3 = xh2[(size_t)r3*64];
              float a0x=bf2f(p0.x), a0y=bf2f(p0.y), d0x=bf2f(p0.z)-a0x, d0y=bf2f(p0.w)-a0y;
              float a1x=bf2f(p1.x), a1y=bf2f(p1.y), d1x=bf2f(p1.z)-a1x, d1y=bf2f(p1.w)-a1y;
              float a2x=bf2f(p2.x), a2y=bf2f(p2.y), d2x=bf2f(p2.z)-a2x, d2y=bf2f(p2.w)-a2y;
              float a3x=bf2f(p3.x), a3y=bf2f(p3.y), d3x=bf2f(p3.z)-a3x, d3y=bf2f(p3.w)-a3y;
              ax = fmaf(bf2f(x0.x), fmaf(f0, d0x, a0x), ax);
              ay = fmaf(bf2f(x0.y), fmaf(f0, d0y, a0y), ay);
              ax = fmaf(bf2f(x1.x), fmaf(f1, d1x, a1x), ax);
              ay = fmaf(bf2f(x1.y), fmaf(f1, d1y, a1y), ay);
              ax = fmaf(bf2f(x2.x), fmaf(f2, d2x, a2x), ax);
              ay = fmaf(bf2f(x2.y), fmaf(f2, d2y, a2y), ay);
              ax = fmaf(bf2f(x3.x), fmaf(f3, d3x, a3x), ax);
              ay = fmaf(bf2f(x3.y), fmaf(f3, d3y, a3y), ay);
            }
            for (; j < cnt; ++j){
              int   r0 = __shfl(s_l, j, 64);
              float t0 = __shfl(t_l, j, 64);
              int i00 = (int)t0; if (i00 > 1023) i00 = 1023;
              float f0 = t0 - (float)i00;
              ushort4 p0 = tabl[(size_t)i00*64];
              ushort2 x0 = xh2[(size_t)r0*64];
              float a0x=bf2f(p0.x), a0y=bf2f(p0.y), d0x=bf2f(p0.z)-a0x, d0y=bf2f(p0.w)-a0y;
              ax = fmaf(bf2f(x0.x), fmaf(f0, d0x, a0x), ax);
              ay = fmaf(bf2f(x0.y), fmaf(f0, d0y, a0y), ay);
            }
          }
          *(float2*)((char*)Sa + swzf((wv*4+i)*512 + lane*8)) = make_float2(ax, ay);
        }
      }
      __syncthreads();

      // ===== phase 2 =====
      bf16x8 ah[4], al[4];
      f32x4 acc[2];

      // ---- stage A: t = ssp(agg @ W2 + b2) ----
      #pragma unroll
      for (int ks=0;ks<4;++ks){
        int lin = m*512 + (ks*32 + g*8)*4;
        split8(*(const float4*)((const char*)Sa + swzf(lin)),
               *(const float4*)((const char*)Sa + swzf(lin + 16)), ah[ks], al[ks]);
      }
      acc[0] = vzero; acc[1] = vzero;
      gemm_hl(w2p, wfo, ah, al, acc);
      {
        const float b20 = B2[colA], b21 = B2[colB];
        #pragma unroll
        for (int r=0;r<4;++r){
          const int row = g*4 + r;
          *(float*)((char*)St + swzf(row*512 + colA*4)) = ssp_f(acc[0][r] + b20);
          *(float*)((char*)St + swzf(row*512 + colB*4)) = ssp_f(acc[1][r] + b21);
        }
      }
      __syncthreads();

      // ---- stage B: h' = h + t @ WL + bl ----
      #pragma unroll
      for (int ks=0;ks<4;++ks){
        int lin = m*512 + (ks*32 + g*8)*4;
        split8(*(const float4*)((const char*)St + swzf(lin)),
               *(const float4*)((const char*)St + swzf(lin + 16)), ah[ks], al[ks]);
      }
      float hr0[4], hr1[4];
      #pragma unroll
      for (int r=0;r<4;++r){
        hr0[r] = Hio[(size_t)(m0 + g*4 + r)*HDIM + colA];
        hr1[r] = Hio[(size_t)(m0 + g*4 + r)*HDIM + colB];
      }
      acc[0] = vzero; acc[1] = vzero;
      gemm_hl(wlp, wfo, ah, al, acc);
      // Sa's last readers were the stage-A frag loads (pre-barrier) -> safe.
      {
        const float bl0 = BL[colA], bl1 = BL[colB];
        #pragma unroll
        for (int r=0;r<4;++r){
          const int row = g*4 + r;
          float v0 = hr0[r] + acc[0][r] + bl0;
          float v1 = hr1[r] + acc[1][r] + bl1;
          Hio[(size_t)(m0+row)*HDIM + colA] = v0;
          Hio[(size_t)(m0+row)*HDIM + colB] = v1;
          if (!last){
            *(float*)((char*)Sa + swzf(row*512 + colA*4)) = v0;
            *(float*)((char*)Sa + swzf(row*512 + colB*4)) = v1;
          }
        }
      }
      if (!last){
        __syncthreads();
        // ---- stage C: xh_next(bf16) = h' @ W1n ----
        #pragma unroll
        for (int ks=0;ks<4;++ks){
          int lin = m*512 + (ks*32 + g*8)*4;
          split8(*(const float4*)((const char*)Sa + swzf(lin)),
                 *(const float4*)((const char*)Sa + swzf(lin + 16)), ah[ks], al[ks]);
        }
        acc[0] = vzero; acc[1] = vzero;
        gemm_hl(w1p, wfo, ah, al, acc);
        #pragma unroll
        for (int r=0;r<4;++r){
          const int row = g*4 + r;
          xnxt[(size_t)(m0+row)*HDIM + colA] = f2bf(acc[0][r]);
          xnxt[(size_t)(m0+row)*HDIM + colB] = f2bf(acc[1][r]);
        }
      }
      __syncthreads();   // Sa/St reused by next tile's phase 1
    }
    grid.sync();
  }

  // ===== output MLP (per node) =====
  for (int tile = blockIdx.x; tile < N_NODES/16; tile += gridDim.x){
    for (int i=0;i<4;++i){
      int node = tile*16 + wv*4 + i;
      float acc = ob1[lane];
      const float* hrow = Hio + (size_t)node*HDIM;
      #pragma unroll 4
      for (int k=0;k<HDIM;++k) acc = fmaf(hrow[k], ow1[k*64 + lane], acc);
      float s = ssp_f(acc) * ow2[lane];
      for (int off=32; off>0; off>>=1) s += __shfl_down(s, off, 64);
      if (lane == 0) nodeval[node] = s + ob2[0];
    }
  }
  grid.sync();

  // ===== graph readout =====
  if (blockIdx.x < NGRAPH){
    int gg = blockIdx.x;
    float s = 0.f;
    for (int n = tid; n < N_NODES; n += 256)
      if (batch[n] == gg) s += nodeval[n];
    for (int off=32; off>0; off>>=1) s += __shfl_down(s, off, 64);
    if ((tid & 63) == 0) sred[tid >> 6] = s;
    __syncthreads();
    if (tid == 0){
      float tot = sred[0] + sred[1] + sred[2] + sred[3];
      out[gg] = 1.0f/(1.0f + __expf(-tot));
    }
  }
}

// ---------------- host ----------------
extern "C" void kernel_launch(void* const* d_in, const int* in_sizes, int n_in,
                              void* d_out, int out_size, void* d_ws, size_t ws_size,
                              hipStream_t stream){
  (void)in_sizes; (void)n_in; (void)out_size;
  const int*   z      = (const int*)  d_in[0];
  const float* pos    = (const float*)d_in[1];
  const int*   ei     = (const int*)  d_in[2];
  const int*   batch  = (const int*)  d_in[3];
  const float* emb    = (const float*)d_in[4];
  const float* mlp_w1 = (const float*)d_in[5];
  const float* mlp_b1 = (const float*)d_in[6];
  const float* mlp_w2 = (const float*)d_in[7];
  const float* mlp_b2 = (const float*)d_in[8];
  const float* cf_w1  = (const float*)d_in[9];
  const float* cf_w2  = (const float*)d_in[10];
  const float* cf_b2  = (const float*)d_in[11];
  const float* lin_w  = (const float*)d_in[12];
  const float* lin_b  = (const float*)d_in[13];
  const float* ow1    = (const float*)d_in[14];
  const float* ob1    = (const float*)d_in[15];
  const float* ow2    = (const float*)d_in[16];
  const float* ob2    = (const float*)d_in[17];

  char* wp = (char*)d_ws;
  size_t used = 0;
  auto alloc = [&](size_t bytes)->char*{
    char* p = wp + used;
    used += (bytes + 1023) & ~(size_t)1023;
    return p;
  };
  ushort4* tabp    = (ushort4*)alloc((size_t)NLAYER*1024*64*8);
  float*   h       = (float*)alloc((size_t)N_NODES*HDIM*4);
  ushort*  xhb0    = (ushort*)alloc((size_t)N_NODES*HDIM*2);
  ushort*  xhb1    = (ushort*)alloc((size_t)N_NODES*HDIM*2);
  ushort*  wpk     = (ushort*)alloc((size_t)36*WPL*2);
  int*     rowptr  = (int*)  alloc((size_t)(N_NODES+1)*4);
  int*     cursor  = (int*)  alloc((size_t)N_NODES*4);
  int*     srcl    = (int*)  alloc((size_t)N_EDGES*4);
  float*   tl      = (float*)alloc((size_t)N_EDGES*4);
  float*   nodeval = (float*)alloc((size_t)N_NODES*4);
  if (used > ws_size) return;

  hipMemsetAsync(cursor, 0, (size_t)N_NODES*4, stream);

  k_setup1<<<K1_GRID, 256, 0, stream>>>(z, emb, h,
      mlp_w1, mlp_b1, mlp_w2, mlp_b2, tabp, ei, cursor, cf_w2, lin_w, cf_w1, wpk);
  k_scan  <<<1, 1024, 0, stream>>>(cursor, rowptr);
  k_fill_xh<<<2048, 256, 0, stream>>>(ei, pos, cursor, srcl, tl, h, cf_w1, (ushort4*)xhb0);

  // cooperative mega-kernel: grid sized to guaranteed co-residency
  int occ = 0;
  if (hipOccupancyMaxActiveBlocksPerMultiprocessor(&occ, k_mega, 256, 0) != hipSuccess || occ < 1)
    occ = 1;
  int nb = occ * 256;                 // 256 CUs on MI355X
  if (nb > N_NODES/16) nb = N_NODES/16;

  float* outp = (float*)d_out;
  void* margs[] = {
    (void*)&rowptr, (void*)&srcl, (void*)&tl, (void*)&tabp,
    (void*)&xhb0, (void*)&xhb1, (void*)&wpk,
    (void*)&cf_b2, (void*)&lin_b, (void*)&h,
    (void*)&ow1, (void*)&ob1, (void*)&ow2, (void*)&ob2,
    (void*)&batch, (void*)&nodeval, (void*)&outp
  };
  hipLaunchCooperativeKernel(k_mega, dim3(nb), dim3(256), margs, 0, stream);
}

// Round 6
// 464.957 us; speedup vs baseline: 2.5762x; 2.5762x over previous
//
#include <hip/hip_runtime.h>
#include <math.h>

#define N_NODES 16384
#define N_EDGES 262144
#define HDIM    128
#define NG50    50
#define NLAYER  6
#define NGRAPH  16
#define TROWS   1025
#define RMAXF   4.34f
#define WPL     16384   // ushorts per packed weight plane (128*128)

__device__ __forceinline__ float ssp_f(float x){
  return (x > 20.0f ? x : log1pf(__expf(x))) - 0.6931471805599453f;
}
__device__ __forceinline__ void fma4(float4& c, float a, const float4 b){
  c.x = fmaf(a,b.x,c.x); c.y = fmaf(a,b.y,c.y); c.z = fmaf(a,b.z,c.z); c.w = fmaf(a,b.w,c.w);
}
// bf16 helpers (RNE)
__device__ __forceinline__ unsigned short f2bf(float x){
  unsigned u = __float_as_uint(x);
  u += 0x7FFF + ((u>>16)&1);
  return (unsigned short)(u>>16);
}
__device__ __forceinline__ float bf2f(unsigned short u){
  return __uint_as_float(((unsigned)u)<<16);
}

// MFMA fragment types
typedef __attribute__((ext_vector_type(8))) short bf16x8;
typedef __attribute__((ext_vector_type(4))) float f32x4;
// LDS XOR swizzle for fp32 [16][128] tiles (512 B rows): involution on 16B
// granules; route EVERY 16B half of a 32B fragment through swzf (R1 lesson).
__device__ __forceinline__ int swzf(int lin){ return lin ^ (((lin>>9)&7)<<4); }

// hi/lo bf16 split of 8 fp32 values (Dekker-style: lo = bf16(x - hi))
__device__ __forceinline__ void split8(const float4 v0, const float4 v1, bf16x8& hi, bf16x8& lo){
  float x[8] = {v0.x,v0.y,v0.z,v0.w,v1.x,v1.y,v1.z,v1.w};
  #pragma unroll
  for (int i=0;i<8;++i){
    unsigned short h = f2bf(x[i]);
    hi[i] = (short)h;
    lo[i] = (short)f2bf(x[i] - bf2f(h));
  }
}

// ================= K1: init_h || tab || hist || wpack =================
#define TAB_R   4
#define TAB_NB  257   // ceil(1025/4)
#define B_INIT  2048
#define B_TAB   1542  // NLAYER*TAB_NB
#define B_HIST  1024
#define B_WPACK 144
#define K1_GRID (B_INIT + B_TAB + B_HIST + B_WPACK)

__global__ __launch_bounds__(256) void k_setup1(
    const int* __restrict__ z, const float* __restrict__ emb, float* __restrict__ h,
    const float* __restrict__ w1, const float* __restrict__ b1,
    const float* __restrict__ w2, const float* __restrict__ b2, float* __restrict__ tab,
    const int* __restrict__ ei, int* __restrict__ cursor,
    const float* __restrict__ cf_w2, const float* __restrict__ lin_w,
    const float* __restrict__ cf_w1, ushort* __restrict__ wp)
{
  __shared__ float ea[TAB_R][52];
  __shared__ float sT[TAB_R][HDIM];
  __shared__ float part[2][TAB_R][HDIM];
  const int b = blockIdx.x;
  const int tid = threadIdx.x;

  if (b < B_INIT){
    int t = b*256 + tid;
    int n = t >> 5, q = t & 31;
    ((float4*)h)[t] = ((const float4*)emb)[(z[n]<<5) + q];
    return;
  }
  if (b < B_INIT + B_TAB){
    int bb = b - B_INIT;
    int l  = bb / TAB_NB;
    int i0 = (bb % TAB_NB) * TAB_R;
    int j    = tid & 127;
    int half = tid >> 7;
    const float* w1l = w1 + (size_t)l*NG50*HDIM;
    const float* w2l = w2 + (size_t)l*HDIM*HDIM;
    float* tabl = tab + (size_t)l*TROWS*HDIM;
    const float STEP = RMAXF/1024.0f;
    const float GS   = 10.0f/49.0f;
    const float GC   = -0.5f/(GS*GS);
    if (tid < TAB_R*NG50){
      int rr = tid / NG50, k = tid - rr*NG50;
      int ri = i0 + rr; if (ri > TROWS-1) ri = TROWS-1;
      float d = ri*STEP - k*GS;
      ea[rr][k] = __expf(GC*d*d);
    }
    __syncthreads();
    {
      float acc[TAB_R] = {0,0,0,0};
      int kb = half*25;
      for (int k=0;k<25;++k){
        float wv = w1l[(kb+k)*HDIM + j];
        #pragma unroll
        for (int r=0;r<TAB_R;++r) acc[r] = fmaf(ea[r][kb+k], wv, acc[r]);
      }
      #pragma unroll
      for (int r=0;r<TAB_R;++r) part[half][r][j] = acc[r];
    }
    __syncthreads();
    {
      float b1v = b1[(size_t)l*HDIM + j];
      #pragma unroll
      for (int rr=0;rr<2;++rr){
        int r = half*2 + rr;
        sT[r][j] = ssp_f(part[0][r][j] + part[1][r][j] + b1v);
      }
    }
    __syncthreads();
    {
      float o[TAB_R] = {0,0,0,0};
      int kb = half*64;
      #pragma unroll 4
      for (int k=0;k<64;++k){
        float wv = w2l[(kb+k)*HDIM + j];
        #pragma unroll
        for (int r=0;r<TAB_R;++r) o[r] = fmaf(sT[r][kb+k], wv, o[r]);
      }
      #pragma unroll
      for (int r=0;r<TAB_R;++r) part[half][r][j] = o[r];
    }
    __syncthreads();
    {
      float b2v = b2[(size_t)l*HDIM + j];
      #pragma unroll
      for (int rr=0;rr<2;++rr){
        int r = half*2 + rr;
        int ri = i0 + r;
        if (ri < TROWS){
          float rv = ri*STEP;
          float C = 0.5f*(cosf(rv*0.31415926535897931f) + 1.0f);
          tabl[(size_t)ri*HDIM + j] = (part[0][r][j] + part[1][r][j] + b2v)*C;
        }
      }
    }
    return;
  }
  if (b < B_INIT + B_TAB + B_HIST){
    int e = (b - (B_INIT + B_TAB))*256 + tid;
    if (e < N_EDGES) atomicAdd(&cursor[ei[N_EDGES + e]], 1);
    return;
  }
  {
    int bb  = b - (B_INIT + B_TAB + B_HIST);   // 0..143 = 18 mats x 8 parts
    int mat = bb >> 3;
    int s   = (bb & 7)*256 + tid;
    const float* M = (mat < 6)  ? cf_w2 + (size_t)mat*HDIM*HDIM
                   : (mat < 12) ? lin_w + (size_t)(mat-6)*HDIM*HDIM
                                : cf_w1 + (size_t)(mat-12)*HDIM*HDIM;
    int ct = s >> 8, ks = (s >> 6) & 3, l = s & 63;
    int col = ct*16 + (l & 15);
    int r0  = ks*32 + (l >> 4)*8;
    ushort oh[8], ol[8];
    #pragma unroll
    for (int i=0;i<8;++i){
      float w = M[(size_t)(r0+i)*HDIM + col];
      oh[i] = f2bf(w);
      ol[i] = f2bf(w - bf2f(oh[i]));
    }
    ushort* dh = wp + (size_t)(2*mat)*WPL + (size_t)s*8;
    ushort* dl = dh + WPL;
    *(ushort4*)(dh+0) = make_ushort4(oh[0],oh[1],oh[2],oh[3]);
    *(ushort4*)(dh+4) = make_ushort4(oh[4],oh[5],oh[6],oh[7]);
    *(ushort4*)(dl+0) = make_ushort4(ol[0],ol[1],ol[2],ol[3]);
    *(ushort4*)(dl+4) = make_ushort4(ol[4],ol[5],ol[6],ol[7]);
  }
}

// ================= K2: scan (block 0) || pack (blocks 1..384) =================
__global__ __launch_bounds__(1024) void k_scan_pack(int* __restrict__ cursor,
    int* __restrict__ rowptr, const float* __restrict__ tab, ushort4* __restrict__ tabp){
  __shared__ int sbuf[1024];
  int t = threadIdx.x;
  if (blockIdx.x == 0){
    int base = t*16;
    int d[16]; int s = 0;
    #pragma unroll
    for (int i=0;i<16;++i){ d[i] = cursor[base+i]; s += d[i]; }
    sbuf[t] = s; __syncthreads();
    for (int off=1; off<1024; off<<=1){
      int v = sbuf[t];
      int add = (t >= off) ? sbuf[t-off] : 0;
      __syncthreads();
      sbuf[t] = v + add;
      __syncthreads();
    }
    int run = (t==0) ? 0 : sbuf[t-1];
    #pragma unroll
    for (int i=0;i<16;++i){ rowptr[base+i] = run; cursor[base+i] = run; run += d[i]; }
    if (t==1023) rowptr[N_NODES] = run;
    return;
  }
  size_t tt = (size_t)(blockIdx.x-1)*1024 + t;   // 384*1024 = NLAYER*1024*64
  int lane = (int)(tt & 63);
  size_t row = tt >> 6;
  size_t l = row >> 10, i = row & 1023;
  const float* a = tab + (l*TROWS + i)*HDIM + lane*2;
  float2 av = *(const float2*)a;
  float2 bv = *(const float2*)(a + HDIM);
  ushort4 p;
  p.x = f2bf(av.x); p.y = f2bf(av.y); p.z = f2bf(bv.x); p.w = f2bf(bv.y);
  tabp[tt] = p;
}

// ================= K3: fill (blocks 0..1023) || gemm_xh (1024..2047) ==========
#define FR 16
__global__ __launch_bounds__(256,4) void k_fill_xh(
    const int* __restrict__ ei, const float* __restrict__ pos,
    int* __restrict__ cursor, int* __restrict__ srcl, float* __restrict__ tl,
    const float* __restrict__ A, const float* __restrict__ B, ushort4* __restrict__ Cb)
{
  __shared__ float Bs[32*HDIM];
  const int tid = threadIdx.x;
  if (blockIdx.x < 1024){
    int e = blockIdx.x*256 + tid;
    if (e < N_EDGES){
      int a = ei[e];
      int c = ei[N_EDGES + e];
      float dx = pos[3*a+0] - pos[3*c+0];
      float dy = pos[3*a+1] - pos[3*c+1];
      float dz = pos[3*a+2] - pos[3*c+2];
      dx -= rintf(dx*0.2f)*5.0f;
      dy -= rintf(dy*0.2f)*5.0f;
      dz -= rintf(dz*0.2f)*5.0f;
      float r = sqrtf(fmaf(dx,dx,fmaf(dy,dy,dz*dz)));
      int slot = atomicAdd(&cursor[c], 1);
      srcl[slot] = a;
      tl[slot]   = r * (1024.0f/RMAXF);
    }
    return;
  }
  // xh(bf16) = h @ cf_w1[0]
  int m0 = (blockIdx.x - 1024)*FR;
  int tc = tid & 31, tr = tid >> 5;
  int j0 = tc*4;
  int lr0 = tr*2, lr1 = tr*2+1;
  float4 acc0 = make_float4(0,0,0,0), acc1 = acc0;
  const float* A0 = A + (size_t)(m0 + lr0)*HDIM;
  const float* A1 = A + (size_t)(m0 + lr1)*HDIM;
  for (int kc=0; kc<HDIM; kc+=32){
    __syncthreads();
    {
      const float4* src = (const float4*)(B + kc*HDIM);
      float4* dst = (float4*)Bs;
      #pragma unroll
      for (int i=0;i<4;++i) dst[tid + i*256] = src[tid + i*256];
    }
    __syncthreads();
    #pragma unroll
    for (int kk=0; kk<32; kk+=4){
      float4 b0 = *(const float4*)(Bs + (kk+0)*HDIM + j0);
      float4 b1 = *(const float4*)(Bs + (kk+1)*HDIM + j0);
      float4 b2 = *(const float4*)(Bs + (kk+2)*HDIM + j0);
      float4 b3 = *(const float4*)(Bs + (kk+3)*HDIM + j0);
      float4 a0 = *(const float4*)(A0 + kc + kk);
      float4 a1 = *(const float4*)(A1 + kc + kk);
      fma4(acc0,a0.x,b0); fma4(acc0,a0.y,b1); fma4(acc0,a0.z,b2); fma4(acc0,a0.w,b3);
      fma4(acc1,a1.x,b0); fma4(acc1,a1.y,b1); fma4(acc1,a1.z,b2); fma4(acc1,a1.w,b3);
    }
  }
  ushort4 o;
  o.x=f2bf(acc0.x); o.y=f2bf(acc0.y); o.z=f2bf(acc0.z); o.w=f2bf(acc0.w);
  Cb[(size_t)(m0 + lr0)*32 + tc] = o;
  o.x=f2bf(acc1.x); o.y=f2bf(acc1.y); o.z=f2bf(acc1.z); o.w=f2bf(acc1.w);
  Cb[(size_t)(m0 + lr1)*32 + tc] = o;
}

// ================= per-layer: agg (LDS) -> 3x MFMA hi/lo stages ==============
// Gather uses 8-edge PRELOAD WINDOWS: all 16 scattered loads of a window are
// issued before any consumption (2x MLP vs the 4-edge unroll). Edge order and
// per-edge fma sequence unchanged -> accumulation is bit-exact vs round 4.
// LAST variant also fuses the output MLP (reads h' rows from LDS, replicating
// k_outA's exact fmaf / shfl_down order).
__device__ __forceinline__ void gemm_hl(const ushort* plane, size_t wfo,
    const bf16x8* ah, const bf16x8* al, f32x4* acc){
  #pragma unroll
  for (int ks=0;ks<4;++ks){
    #pragma unroll
    for (int c=0;c<2;++c){
      const ushort* p = plane + wfo + (size_t)(c*4+ks)*512;
      bf16x8 wh = *(const bf16x8*)p;
      bf16x8 wl = *(const bf16x8*)(p + WPL);
      acc[c] = __builtin_amdgcn_mfma_f32_16x16x32_bf16(ah[ks], wh, acc[c], 0,0,0);
      acc[c] = __builtin_amdgcn_mfma_f32_16x16x32_bf16(al[ks], wh, acc[c], 0,0,0);
      acc[c] = __builtin_amdgcn_mfma_f32_16x16x32_bf16(ah[ks], wl, acc[c], 0,0,0);
    }
  }
}
template<bool LAST>
__global__ __launch_bounds__(256,4) void k_layer(
    const int* __restrict__ rowptr, const int* __restrict__ srcl, const float* __restrict__ tl,
    const ushort4* __restrict__ tabp, const ushort2* __restrict__ xh_cur,
    const ushort* __restrict__ w2p, const float* __restrict__ B2,
    const ushort* __restrict__ wlp, const float* __restrict__ BL,
    float* __restrict__ Hio, const ushort* __restrict__ w1p, ushort* __restrict__ xh_nxt,
    const float* __restrict__ ow1, const float* __restrict__ ob1,
    const float* __restrict__ ow2, const float* __restrict__ ob2,
    float* __restrict__ nodeval)
{
  __shared__ alignas(16) float Sa[16*HDIM];   // 8 KB: agg, then h'
  __shared__ alignas(16) float St[16*HDIM];   // 8 KB: t
  const int tid  = threadIdx.x;
  const int wv   = tid >> 6, lane = tid & 63;
  const int m0   = blockIdx.x * 16;

  // ===== phase 1: aggregate 4 nodes per wave (8-edge preload windows) =====
  {
    const ushort4* tabl = tabp + lane;
    const ushort2* xh2  = xh_cur + lane;
    for (int i=0;i<4;++i){
      int c = m0 + wv*4 + i;
      int beg = rowptr[c], end = rowptr[c+1];
      float ax = 0.f, ay = 0.f;
      for (int k0 = beg; k0 < end; k0 += 64){
        int rem = end - k0;
        int cnt = rem < 64 ? rem : 64;
        int   s_l = 0; float t_l = 0.f;
        if (lane < cnt){ s_l = srcl[k0+lane]; t_l = tl[k0+lane]; }
        for (int w = 0; w < cnt; w += 8){
          int wc = cnt - w; if (wc > 8) wc = 8;
          ushort4 pp[8]; ushort2 xx[8]; float ff[8];
          #pragma unroll
          for (int e=0;e<8;++e){
            if (e < wc){
              int   rE = __shfl(s_l, w+e, 64);
              float tE = __shfl(t_l, w+e, 64);
              int iE = (int)tE; if (iE > 1023) iE = 1023;
              ff[e] = tE - (float)iE;
              pp[e] = tabl[(size_t)iE*64];
              xx[e] = xh2[(size_t)rE*64];
            }
          }
          #pragma unroll
          for (int e=0;e<8;++e){
            if (e < wc){
              float aX=bf2f(pp[e].x), aY=bf2f(pp[e].y);
              float dX=bf2f(pp[e].z)-aX, dY=bf2f(pp[e].w)-aY;
              ax = fmaf(bf2f(xx[e].x), fmaf(ff[e], dX, aX), ax);
              ay = fmaf(bf2f(xx[e].y), fmaf(ff[e], dY, aY), ay);
            }
          }
        }
      }
      *(float2*)((char*)Sa + swzf((wv*4+i)*512 + lane*8)) = make_float2(ax, ay);
    }
  }
  __syncthreads();

  // ===== phase 2 =====
  const int m = lane & 15, g = lane >> 4;
  const int colA = wv*32 + m;
  const int colB = colA + 16;
  const size_t wfo = (size_t)(wv*8*64 + lane)*8;
  const f32x4 vzero = {0.f,0.f,0.f,0.f};
  bf16x8 ah[4], al[4];
  f32x4 acc[2];

  // ---- stage A: t = ssp(agg @ W2 + b2) ----
  #pragma unroll
  for (int ks=0;ks<4;++ks){
    int lin = m*512 + (ks*32 + g*8)*4;
    split8(*(const float4*)((const char*)Sa + swzf(lin)),
           *(const float4*)((const char*)Sa + swzf(lin + 16)), ah[ks], al[ks]);
  }
  acc[0] = vzero; acc[1] = vzero;
  gemm_hl(w2p, wfo, ah, al, acc);
  {
    const float b20 = B2[colA], b21 = B2[colB];
    #pragma unroll
    for (int r=0;r<4;++r){
      const int row = g*4 + r;
      *(float*)((char*)St + swzf(row*512 + colA*4)) = ssp_f(acc[0][r] + b20);
      *(float*)((char*)St + swzf(row*512 + colB*4)) = ssp_f(acc[1][r] + b21);
    }
  }
  __syncthreads();

  // ---- stage B: h' = h + t @ WL + bl ----
  #pragma unroll
  for (int ks=0;ks<4;++ks){
    int lin = m*512 + (ks*32 + g*8)*4;
    split8(*(const float4*)((const char*)St + swzf(lin)),
           *(const float4*)((const char*)St + swzf(lin + 16)), ah[ks], al[ks]);
  }
  float hr0[4], hr1[4];
  #pragma unroll
  for (int r=0;r<4;++r){
    hr0[r] = Hio[(size_t)(m0 + g*4 + r)*HDIM + colA];
    hr1[r] = Hio[(size_t)(m0 + g*4 + r)*HDIM + colB];
  }
  acc[0] = vzero; acc[1] = vzero;
  gemm_hl(wlp, wfo, ah, al, acc);
  // Sa's last readers were the stage-A frag loads (pre-barrier) -> safe.
  {
    const float bl0 = BL[colA], bl1 = BL[colB];
    #pragma unroll
    for (int r=0;r<4;++r){
      const int row = g*4 + r;
      float v0 = hr0[r] + acc[0][r] + bl0;
      float v1 = hr1[r] + acc[1][r] + bl1;
      Hio[(size_t)(m0+row)*HDIM + colA] = v0;
      Hio[(size_t)(m0+row)*HDIM + colB] = v1;
      *(float*)((char*)Sa + swzf(row*512 + colA*4)) = v0;
      *(float*)((char*)Sa + swzf(row*512 + colB*4)) = v1;
    }
  }
  __syncthreads();

  if (LAST){
    // ---- fused output MLP: nodeval = ssp(h' @ ow1 + ob1) @ ow2 + ob2 ----
    // Exact replication of k_outA's order: k ascending fmaf, shfl_down tree.
    for (int i=0;i<4;++i){
      const int row  = wv*4 + i;
      const int node = m0 + row;
      float acc1 = ob1[lane];
      #pragma unroll 4
      for (int k=0;k<HDIM;++k){
        float hv = *(const float*)((const char*)Sa + swzf(row*512 + k*4));
        acc1 = fmaf(hv, ow1[k*64 + lane], acc1);
      }
      float s = ssp_f(acc1) * ow2[lane];
      for (int off=32; off>0; off>>=1) s += __shfl_down(s, off, 64);
      if (lane == 0) nodeval[node] = s + ob2[0];
    }
    return;
  }

  // ---- stage C: xh_next(bf16) = h' @ W1n ----
  #pragma unroll
  for (int ks=0;ks<4;++ks){
    int lin = m*512 + (ks*32 + g*8)*4;
    split8(*(const float4*)((const char*)Sa + swzf(lin)),
           *(const float4*)((const char*)Sa + swzf(lin + 16)), ah[ks], al[ks]);
  }
  acc[0] = vzero; acc[1] = vzero;
  gemm_hl(w1p, wfo, ah, al, acc);
  #pragma unroll
  for (int r=0;r<4;++r){
    const int row = g*4 + r;
    xh_nxt[(size_t)(m0+row)*HDIM + colA] = f2bf(acc[0][r]);
    xh_nxt[(size_t)(m0+row)*HDIM + colB] = f2bf(acc[1][r]);
  }
}

// ---------------- graph readout ----------------
__global__ __launch_bounds__(256) void k_outB(const float* __restrict__ nodeval,
    const int* __restrict__ batch, float* __restrict__ out){
  __shared__ float sred[4];
  int g = blockIdx.x;
  int t = threadIdx.x;
  float s = 0.f;
  for (int n = t; n < N_NODES; n += 256)
    if (batch[n] == g) s += nodeval[n];
  for (int off=32; off>0; off>>=1) s += __shfl_down(s, off, 64);
  if ((t & 63) == 0) sred[t >> 6] = s;
  __syncthreads();
  if (t == 0){
    float tot = sred[0] + sred[1] + sred[2] + sred[3];
    out[g] = 1.0f/(1.0f + __expf(-tot));
  }
}

// ---------------- host ----------------
extern "C" void kernel_launch(void* const* d_in, const int* in_sizes, int n_in,
                              void* d_out, int out_size, void* d_ws, size_t ws_size,
                              hipStream_t stream){
  (void)in_sizes; (void)n_in; (void)out_size;
  const int*   z      = (const int*)  d_in[0];
  const float* pos    = (const float*)d_in[1];
  const int*   ei     = (const int*)  d_in[2];
  const int*   batch  = (const int*)  d_in[3];
  const float* emb    = (const float*)d_in[4];
  const float* mlp_w1 = (const float*)d_in[5];
  const float* mlp_b1 = (const float*)d_in[6];
  const float* mlp_w2 = (const float*)d_in[7];
  const float* mlp_b2 = (const float*)d_in[8];
  const float* cf_w1  = (const float*)d_in[9];
  const float* cf_w2  = (const float*)d_in[10];
  const float* cf_b2  = (const float*)d_in[11];
  const float* lin_w  = (const float*)d_in[12];
  const float* lin_b  = (const float*)d_in[13];
  const float* ow1    = (const float*)d_in[14];
  const float* ob1    = (const float*)d_in[15];
  const float* ow2    = (const float*)d_in[16];
  const float* ob2    = (const float*)d_in[17];

  char* wp = (char*)d_ws;
  size_t used = 0;
  auto alloc = [&](size_t bytes)->char*{
    char* p = wp + used;
    used += (bytes + 1023) & ~(size_t)1023;
    return p;
  };
  float*   tab     = (float*)alloc((size_t)NLAYER*TROWS*HDIM*4);
  ushort4* tabp    = (ushort4*)alloc((size_t)NLAYER*1024*64*8);
  float*   h       = (float*)alloc((size_t)N_NODES*HDIM*4);
  ushort*  xhb0    = (ushort*)alloc((size_t)N_NODES*HDIM*2);
  ushort*  xhb1    = (ushort*)alloc((size_t)N_NODES*HDIM*2);
  ushort*  wpk     = (ushort*)alloc((size_t)36*WPL*2);
  int*     rowptr  = (int*)  alloc((size_t)(N_NODES+1)*4);
  int*     cursor  = (int*)  alloc((size_t)N_NODES*4);
  int*     srcl    = (int*)  alloc((size_t)N_EDGES*4);
  float*   tl      = (float*)alloc((size_t)N_EDGES*4);
  float*   nodeval = (float*)alloc((size_t)N_NODES*4);
  if (used > ws_size) return;

  hipMemsetAsync(cursor, 0, (size_t)N_NODES*4, stream);

  k_setup1<<<K1_GRID, 256, 0, stream>>>(z, emb, h,
      mlp_w1, mlp_b1, mlp_w2, mlp_b2, tab, ei, cursor, cf_w2, lin_w, cf_w1, wpk);
  k_scan_pack<<<385, 1024, 0, stream>>>(cursor, rowptr, tab, tabp);
  k_fill_xh<<<2048, 256, 0, stream>>>(ei, pos, cursor, srcl, tl, h, cf_w1, (ushort4*)xhb0);

  for (int l=0; l<NLAYER; ++l){
    const ushort* w2p = wpk + (size_t)(2*l)*WPL;        // cf_w2[l]
    const ushort* wlp = wpk + (size_t)(2*(6+l))*WPL;    // lin_w[l]
    const ushort2* xcur = (const ushort2*)((l & 1) ? xhb1 : xhb0);
    ushort*        xnxt = (l & 1) ? xhb0 : xhb1;
    if (l < NLAYER-1){
      const ushort* w1p = wpk + (size_t)(2*(13+l))*WPL; // cf_w1[l+1]
      k_layer<false><<<N_NODES/16, 256, 0, stream>>>(rowptr, srcl, tl,
                 tabp + (size_t)l*1024*64, xcur,
                 w2p, cf_b2 + (size_t)l*HDIM, wlp, lin_b + (size_t)l*HDIM, h,
                 w1p, xnxt, nullptr, nullptr, nullptr, nullptr, nullptr);
    } else {
      k_layer<true><<<N_NODES/16, 256, 0, stream>>>(rowptr, srcl, tl,
                 tabp + (size_t)l*1024*64, xcur,
                 w2p, cf_b2 + (size_t)l*HDIM, wlp, lin_b + (size_t)l*HDIM, h,
                 nullptr, nullptr, ow1, ob1, ow2, ob2, nodeval);
    }
  }
  k_outB  <<<NGRAPH, 256, 0, stream>>>(nodeval, batch, (float*)d_out);
}

// Round 7
// 374.081 us; speedup vs baseline: 3.2021x; 1.2429x over previous
//
#include <hip/hip_runtime.h>
#include <math.h>

#define N_NODES 16384
#define N_EDGES 262144
#define HDIM    128
#define NG50    50
#define NLAYER  6
#define NGRAPH  16
#define TROWS   1025
#define RMAXF   4.34f
#define WPL     16384   // ushorts per packed weight plane (128*128)

__device__ __forceinline__ float ssp_f(float x){
  return (x > 20.0f ? x : log1pf(__expf(x))) - 0.6931471805599453f;
}
__device__ __forceinline__ void fma4(float4& c, float a, const float4 b){
  c.x = fmaf(a,b.x,c.x); c.y = fmaf(a,b.y,c.y); c.z = fmaf(a,b.z,c.z); c.w = fmaf(a,b.w,c.w);
}
// bf16 helpers (RNE)
__device__ __forceinline__ unsigned short f2bf(float x){
  unsigned u = __float_as_uint(x);
  u += 0x7FFF + ((u>>16)&1);
  return (unsigned short)(u>>16);
}
__device__ __forceinline__ float bf2f(unsigned short u){
  return __uint_as_float(((unsigned)u)<<16);
}

// MFMA fragment types
typedef __attribute__((ext_vector_type(8))) short bf16x8;
typedef __attribute__((ext_vector_type(4))) float f32x4;
// LDS XOR swizzle for fp32 [16][128] tiles (512 B rows): involution on 16B
// granules; route EVERY 16B half of a 32B fragment through swzf (R1 lesson).
__device__ __forceinline__ int swzf(int lin){ return lin ^ (((lin>>9)&7)<<4); }

// hi/lo bf16 split of 8 fp32 values (Dekker-style: lo = bf16(x - hi))
__device__ __forceinline__ void split8(const float4 v0, const float4 v1, bf16x8& hi, bf16x8& lo){
  float x[8] = {v0.x,v0.y,v0.z,v0.w,v1.x,v1.y,v1.z,v1.w};
  #pragma unroll
  for (int i=0;i<8;++i){
    unsigned short h = f2bf(x[i]);
    hi[i] = (short)h;
    lo[i] = (short)f2bf(x[i] - bf2f(h));
  }
}

// ================= K1: init_h || tab || hist || wpack =================
#define TAB_R   4
#define TAB_NB  257   // ceil(1025/4)
#define B_INIT  2048
#define B_TAB   1542  // NLAYER*TAB_NB
#define B_HIST  1024
#define B_WPACK 144
#define K1_GRID (B_INIT + B_TAB + B_HIST + B_WPACK)

__global__ __launch_bounds__(256) void k_setup1(
    const int* __restrict__ z, const float* __restrict__ emb, float* __restrict__ h,
    const float* __restrict__ w1, const float* __restrict__ b1,
    const float* __restrict__ w2, const float* __restrict__ b2, float* __restrict__ tab,
    const int* __restrict__ ei, int* __restrict__ cursor,
    const float* __restrict__ cf_w2, const float* __restrict__ lin_w,
    const float* __restrict__ cf_w1, ushort* __restrict__ wp)
{
  __shared__ float ea[TAB_R][52];
  __shared__ float sT[TAB_R][HDIM];
  __shared__ float part[2][TAB_R][HDIM];
  const int b = blockIdx.x;
  const int tid = threadIdx.x;

  if (b < B_INIT){
    int t = b*256 + tid;
    int n = t >> 5, q = t & 31;
    ((float4*)h)[t] = ((const float4*)emb)[(z[n]<<5) + q];
    return;
  }
  if (b < B_INIT + B_TAB){
    int bb = b - B_INIT;
    int l  = bb / TAB_NB;
    int i0 = (bb % TAB_NB) * TAB_R;
    int j    = tid & 127;
    int half = tid >> 7;
    const float* w1l = w1 + (size_t)l*NG50*HDIM;
    const float* w2l = w2 + (size_t)l*HDIM*HDIM;
    float* tabl = tab + (size_t)l*TROWS*HDIM;
    const float STEP = RMAXF/1024.0f;
    const float GS   = 10.0f/49.0f;
    const float GC   = -0.5f/(GS*GS);
    if (tid < TAB_R*NG50){
      int rr = tid / NG50, k = tid - rr*NG50;
      int ri = i0 + rr; if (ri > TROWS-1) ri = TROWS-1;
      float d = ri*STEP - k*GS;
      ea[rr][k] = __expf(GC*d*d);
    }
    __syncthreads();
    {
      float acc[TAB_R] = {0,0,0,0};
      int kb = half*25;
      for (int k=0;k<25;++k){
        float wv = w1l[(kb+k)*HDIM + j];
        #pragma unroll
        for (int r=0;r<TAB_R;++r) acc[r] = fmaf(ea[r][kb+k], wv, acc[r]);
      }
      #pragma unroll
      for (int r=0;r<TAB_R;++r) part[half][r][j] = acc[r];
    }
    __syncthreads();
    {
      float b1v = b1[(size_t)l*HDIM + j];
      #pragma unroll
      for (int rr=0;rr<2;++rr){
        int r = half*2 + rr;
        sT[r][j] = ssp_f(part[0][r][j] + part[1][r][j] + b1v);
      }
    }
    __syncthreads();
    {
      float o[TAB_R] = {0,0,0,0};
      int kb = half*64;
      #pragma unroll 4
      for (int k=0;k<64;++k){
        float wv = w2l[(kb+k)*HDIM + j];
        #pragma unroll
        for (int r=0;r<TAB_R;++r) o[r] = fmaf(sT[r][kb+k], wv, o[r]);
      }
      #pragma unroll
      for (int r=0;r<TAB_R;++r) part[half][r][j] = o[r];
    }
    __syncthreads();
    {
      float b2v = b2[(size_t)l*HDIM + j];
      #pragma unroll
      for (int rr=0;rr<2;++rr){
        int r = half*2 + rr;
        int ri = i0 + r;
        if (ri < TROWS){
          float rv = ri*STEP;
          float C = 0.5f*(cosf(rv*0.31415926535897931f) + 1.0f);
          tabl[(size_t)ri*HDIM + j] = (part[0][r][j] + part[1][r][j] + b2v)*C;
        }
      }
    }
    return;
  }
  if (b < B_INIT + B_TAB + B_HIST){
    int e = (b - (B_INIT + B_TAB))*256 + tid;
    if (e < N_EDGES) atomicAdd(&cursor[ei[N_EDGES + e]], 1);
    return;
  }
  {
    int bb  = b - (B_INIT + B_TAB + B_HIST);   // 0..143 = 18 mats x 8 parts
    int mat = bb >> 3;
    int s   = (bb & 7)*256 + tid;
    const float* M = (mat < 6)  ? cf_w2 + (size_t)mat*HDIM*HDIM
                   : (mat < 12) ? lin_w + (size_t)(mat-6)*HDIM*HDIM
                                : cf_w1 + (size_t)(mat-12)*HDIM*HDIM;
    int ct = s >> 8, ks = (s >> 6) & 3, l = s & 63;
    int col = ct*16 + (l & 15);
    int r0  = ks*32 + (l >> 4)*8;
    ushort oh[8], ol[8];
    #pragma unroll
    for (int i=0;i<8;++i){
      float w = M[(size_t)(r0+i)*HDIM + col];
      oh[i] = f2bf(w);
      ol[i] = f2bf(w - bf2f(oh[i]));
    }
    ushort* dh = wp + (size_t)(2*mat)*WPL + (size_t)s*8;
    ushort* dl = dh + WPL;
    *(ushort4*)(dh+0) = make_ushort4(oh[0],oh[1],oh[2],oh[3]);
    *(ushort4*)(dh+4) = make_ushort4(oh[4],oh[5],oh[6],oh[7]);
    *(ushort4*)(dl+0) = make_ushort4(ol[0],ol[1],ol[2],ol[3]);
    *(ushort4*)(dl+4) = make_ushort4(ol[4],ol[5],ol[6],ol[7]);
  }
}

// ================= K2: scan (block 0) || pack (blocks 1..384) =================
__global__ __launch_bounds__(1024) void k_scan_pack(int* __restrict__ cursor,
    int* __restrict__ rowptr, const float* __restrict__ tab, ushort4* __restrict__ tabp){
  __shared__ int sbuf[1024];
  int t = threadIdx.x;
  if (blockIdx.x == 0){
    int base = t*16;
    int d[16]; int s = 0;
    #pragma unroll
    for (int i=0;i<16;++i){ d[i] = cursor[base+i]; s += d[i]; }
    sbuf[t] = s; __syncthreads();
    for (int off=1; off<1024; off<<=1){
      int v = sbuf[t];
      int add = (t >= off) ? sbuf[t-off] : 0;
      __syncthreads();
      sbuf[t] = v + add;
      __syncthreads();
    }
    int run = (t==0) ? 0 : sbuf[t-1];
    #pragma unroll
    for (int i=0;i<16;++i){ rowptr[base+i] = run; cursor[base+i] = run; run += d[i]; }
    if (t==1023) rowptr[N_NODES] = run;
    return;
  }
  size_t tt = (size_t)(blockIdx.x-1)*1024 + t;   // 384*1024 = NLAYER*1024*64
  int lane = (int)(tt & 63);
  size_t row = tt >> 6;
  size_t l = row >> 10, i = row & 1023;
  const float* a = tab + (l*TROWS + i)*HDIM + lane*2;
  float2 av = *(const float2*)a;
  float2 bv = *(const float2*)(a + HDIM);
  ushort4 p;
  p.x = f2bf(av.x); p.y = f2bf(av.y); p.z = f2bf(bv.x); p.w = f2bf(bv.y);
  tabp[tt] = p;
}

// ================= K3: fill (blocks 0..1023) || gemm_xh (1024..2047) ==========
#define FR 16
__global__ __launch_bounds__(256,4) void k_fill_xh(
    const int* __restrict__ ei, const float* __restrict__ pos,
    int* __restrict__ cursor, int* __restrict__ srcl, float* __restrict__ tl,
    const float* __restrict__ A, const float* __restrict__ B, ushort4* __restrict__ Cb)
{
  __shared__ float Bs[32*HDIM];
  const int tid = threadIdx.x;
  if (blockIdx.x < 1024){
    int e = blockIdx.x*256 + tid;
    if (e < N_EDGES){
      int a = ei[e];
      int c = ei[N_EDGES + e];
      float dx = pos[3*a+0] - pos[3*c+0];
      float dy = pos[3*a+1] - pos[3*c+1];
      float dz = pos[3*a+2] - pos[3*c+2];
      dx -= rintf(dx*0.2f)*5.0f;
      dy -= rintf(dy*0.2f)*5.0f;
      dz -= rintf(dz*0.2f)*5.0f;
      float r = sqrtf(fmaf(dx,dx,fmaf(dy,dy,dz*dz)));
      int slot = atomicAdd(&cursor[c], 1);
      srcl[slot] = a;
      tl[slot]   = r * (1024.0f/RMAXF);
    }
    return;
  }
  // xh(bf16) = h @ cf_w1[0]
  int m0 = (blockIdx.x - 1024)*FR;
  int tc = tid & 31, tr = tid >> 5;
  int j0 = tc*4;
  int lr0 = tr*2, lr1 = tr*2+1;
  float4 acc0 = make_float4(0,0,0,0), acc1 = acc0;
  const float* A0 = A + (size_t)(m0 + lr0)*HDIM;
  const float* A1 = A + (size_t)(m0 + lr1)*HDIM;
  for (int kc=0; kc<HDIM; kc+=32){
    __syncthreads();
    {
      const float4* src = (const float4*)(B + kc*HDIM);
      float4* dst = (float4*)Bs;
      #pragma unroll
      for (int i=0;i<4;++i) dst[tid + i*256] = src[tid + i*256];
    }
    __syncthreads();
    #pragma unroll
    for (int kk=0; kk<32; kk+=4){
      float4 b0 = *(const float4*)(Bs + (kk+0)*HDIM + j0);
      float4 b1 = *(const float4*)(Bs + (kk+1)*HDIM + j0);
      float4 b2 = *(const float4*)(Bs + (kk+2)*HDIM + j0);
      float4 b3 = *(const float4*)(Bs + (kk+3)*HDIM + j0);
      float4 a0 = *(const float4*)(A0 + kc + kk);
      float4 a1 = *(const float4*)(A1 + kc + kk);
      fma4(acc0,a0.x,b0); fma4(acc0,a0.y,b1); fma4(acc0,a0.z,b2); fma4(acc0,a0.w,b3);
      fma4(acc1,a1.x,b0); fma4(acc1,a1.y,b1); fma4(acc1,a1.z,b2); fma4(acc1,a1.w,b3);
    }
  }
  ushort4 o;
  o.x=f2bf(acc0.x); o.y=f2bf(acc0.y); o.z=f2bf(acc0.z); o.w=f2bf(acc0.w);
  Cb[(size_t)(m0 + lr0)*32 + tc] = o;
  o.x=f2bf(acc1.x); o.y=f2bf(acc1.y); o.z=f2bf(acc1.z); o.w=f2bf(acc1.w);
  Cb[(size_t)(m0 + lr1)*32 + tc] = o;
}

// ================= per-layer: agg (LDS) -> 3x MFMA hi/lo stages ==============
// Gather: STRAIGHT-LINE 8-edge unroll with named scalars (no arrays, no guards
// in the body -> stays in registers; R6's guarded-array version collapsed to
// VGPR=36 + serialization). All 16 scattered loads issue before consumption.
// Edge order and per-edge fma sequence identical to R4 -> bit-exact.
__device__ __forceinline__ void gemm_hl(const ushort* plane, size_t wfo,
    const bf16x8* ah, const bf16x8* al, f32x4* acc){
  #pragma unroll
  for (int ks=0;ks<4;++ks){
    #pragma unroll
    for (int c=0;c<2;++c){
      const ushort* p = plane + wfo + (size_t)(c*4+ks)*512;
      bf16x8 wh = *(const bf16x8*)p;
      bf16x8 wl = *(const bf16x8*)(p + WPL);
      acc[c] = __builtin_amdgcn_mfma_f32_16x16x32_bf16(ah[ks], wh, acc[c], 0,0,0);
      acc[c] = __builtin_amdgcn_mfma_f32_16x16x32_bf16(al[ks], wh, acc[c], 0,0,0);
      acc[c] = __builtin_amdgcn_mfma_f32_16x16x32_bf16(ah[ks], wl, acc[c], 0,0,0);
    }
  }
}
template<bool LAST>
__global__ __launch_bounds__(256,4) void k_layer(
    const int* __restrict__ rowptr, const int* __restrict__ srcl, const float* __restrict__ tl,
    const ushort4* __restrict__ tabp, const ushort2* __restrict__ xh_cur,
    const ushort* __restrict__ w2p, const float* __restrict__ B2,
    const ushort* __restrict__ wlp, const float* __restrict__ BL,
    float* __restrict__ Hio, const ushort* __restrict__ w1p, ushort* __restrict__ xh_nxt,
    const float* __restrict__ ow1, const float* __restrict__ ob1,
    const float* __restrict__ ow2, const float* __restrict__ ob2,
    float* __restrict__ nodeval)
{
  __shared__ alignas(16) float Sa[16*HDIM];   // 8 KB: agg, then h'
  __shared__ alignas(16) float St[16*HDIM];   // 8 KB: t
  const int tid  = threadIdx.x;
  const int wv   = tid >> 6, lane = tid & 63;
  const int m0   = blockIdx.x * 16;

  // ===== phase 1: aggregate 4 nodes per wave (straight-line 8-edge unroll) ===
  {
    const ushort4* tabl = tabp + lane;
    const ushort2* xh2  = xh_cur + lane;
    for (int i=0;i<4;++i){
      int c = m0 + wv*4 + i;
      int beg = rowptr[c], end = rowptr[c+1];
      float ax = 0.f, ay = 0.f;
      for (int k0 = beg; k0 < end; k0 += 64){
        int rem = end - k0;
        int cnt = rem < 64 ? rem : 64;
        int   s_l = 0; float t_l = 0.f;
        if (lane < cnt){ s_l = srcl[k0+lane]; t_l = tl[k0+lane]; }
        int j = 0;
        for (; j+7 < cnt; j += 8){
          int   r0 = __shfl(s_l, j,   64); float t0 = __shfl(t_l, j,   64);
          int   r1 = __shfl(s_l, j+1, 64); float t1 = __shfl(t_l, j+1, 64);
          int   r2 = __shfl(s_l, j+2, 64); float t2 = __shfl(t_l, j+2, 64);
          int   r3 = __shfl(s_l, j+3, 64); float t3 = __shfl(t_l, j+3, 64);
          int   r4 = __shfl(s_l, j+4, 64); float t4 = __shfl(t_l, j+4, 64);
          int   r5 = __shfl(s_l, j+5, 64); float t5 = __shfl(t_l, j+5, 64);
          int   r6 = __shfl(s_l, j+6, 64); float t6 = __shfl(t_l, j+6, 64);
          int   r7 = __shfl(s_l, j+7, 64); float t7 = __shfl(t_l, j+7, 64);
          int i00 = (int)t0; if (i00 > 1023) i00 = 1023;
          int i01 = (int)t1; if (i01 > 1023) i01 = 1023;
          int i02 = (int)t2; if (i02 > 1023) i02 = 1023;
          int i03 = (int)t3; if (i03 > 1023) i03 = 1023;
          int i04 = (int)t4; if (i04 > 1023) i04 = 1023;
          int i05 = (int)t5; if (i05 > 1023) i05 = 1023;
          int i06 = (int)t6; if (i06 > 1023) i06 = 1023;
          int i07 = (int)t7; if (i07 > 1023) i07 = 1023;
          float f0 = t0 - (float)i00;
          float f1 = t1 - (float)i01;
          float f2 = t2 - (float)i02;
          float f3 = t3 - (float)i03;
          float f4 = t4 - (float)i04;
          float f5 = t5 - (float)i05;
          float f6 = t6 - (float)i06;
          float f7 = t7 - (float)i07;
          ushort4 p0 = tabl[(size_t)i00*64];
          ushort4 p1 = tabl[(size_t)i01*64];
          ushort4 p2 = tabl[(size_t)i02*64];
          ushort4 p3 = tabl[(size_t)i03*64];
          ushort4 p4 = tabl[(size_t)i04*64];
          ushort4 p5 = tabl[(size_t)i05*64];
          ushort4 p6 = tabl[(size_t)i06*64];
          ushort4 p7 = tabl[(size_t)i07*64];
          ushort2 x0 = xh2[(size_t)r0*64];
          ushort2 x1 = xh2[(size_t)r1*64];
          ushort2 x2 = xh2[(size_t)r2*64];
          ushort2 x3 = xh2[(size_t)r3*64];
          ushort2 x4 = xh2[(size_t)r4*64];
          ushort2 x5 = xh2[(size_t)r5*64];
          ushort2 x6 = xh2[(size_t)r6*64];
          ushort2 x7 = xh2[(size_t)r7*64];
          float aX, aY, dX, dY;
          aX=bf2f(p0.x); aY=bf2f(p0.y); dX=bf2f(p0.z)-aX; dY=bf2f(p0.w)-aY;
          ax = fmaf(bf2f(x0.x), fmaf(f0, dX, aX), ax);
          ay = fmaf(bf2f(x0.y), fmaf(f0, dY, aY), ay);
          aX=bf2f(p1.x); aY=bf2f(p1.y); dX=bf2f(p1.z)-aX; dY=bf2f(p1.w)-aY;
          ax = fmaf(bf2f(x1.x), fmaf(f1, dX, aX), ax);
          ay = fmaf(bf2f(x1.y), fmaf(f1, dY, aY), ay);
          aX=bf2f(p2.x); aY=bf2f(p2.y); dX=bf2f(p2.z)-aX; dY=bf2f(p2.w)-aY;
          ax = fmaf(bf2f(x2.x), fmaf(f2, dX, aX), ax);
          ay = fmaf(bf2f(x2.y), fmaf(f2, dY, aY), ay);
          aX=bf2f(p3.x); aY=bf2f(p3.y); dX=bf2f(p3.z)-aX; dY=bf2f(p3.w)-aY;
          ax = fmaf(bf2f(x3.x), fmaf(f3, dX, aX), ax);
          ay = fmaf(bf2f(x3.y), fmaf(f3, dY, aY), ay);
          aX=bf2f(p4.x); aY=bf2f(p4.y); dX=bf2f(p4.z)-aX; dY=bf2f(p4.w)-aY;
          ax = fmaf(bf2f(x4.x), fmaf(f4, dX, aX), ax);
          ay = fmaf(bf2f(x4.y), fmaf(f4, dY, aY), ay);
          aX=bf2f(p5.x); aY=bf2f(p5.y); dX=bf2f(p5.z)-aX; dY=bf2f(p5.w)-aY;
          ax = fmaf(bf2f(x5.x), fmaf(f5, dX, aX), ax);
          ay = fmaf(bf2f(x5.y), fmaf(f5, dY, aY), ay);
          aX=bf2f(p6.x); aY=bf2f(p6.y); dX=bf2f(p6.z)-aX; dY=bf2f(p6.w)-aY;
          ax = fmaf(bf2f(x6.x), fmaf(f6, dX, aX), ax);
          ay = fmaf(bf2f(x6.y), fmaf(f6, dY, aY), ay);
          aX=bf2f(p7.x); aY=bf2f(p7.y); dX=bf2f(p7.z)-aX; dY=bf2f(p7.w)-aY;
          ax = fmaf(bf2f(x7.x), fmaf(f7, dX, aX), ax);
          ay = fmaf(bf2f(x7.y), fmaf(f7, dY, aY), ay);
        }
        for (; j+3 < cnt; j += 4){
          int   r0 = __shfl(s_l, j,   64); float t0 = __shfl(t_l, j,   64);
          int   r1 = __shfl(s_l, j+1, 64); float t1 = __shfl(t_l, j+1, 64);
          int   r2 = __shfl(s_l, j+2, 64); float t2 = __shfl(t_l, j+2, 64);
          int   r3 = __shfl(s_l, j+3, 64); float t3 = __shfl(t_l, j+3, 64);
          int i00 = (int)t0; if (i00 > 1023) i00 = 1023;
          int i01 = (int)t1; if (i01 > 1023) i01 = 1023;
          int i02 = (int)t2; if (i02 > 1023) i02 = 1023;
          int i03 = (int)t3; if (i03 > 1023) i03 = 1023;
          float f0 = t0 - (float)i00;
          float f1 = t1 - (float)i01;
          float f2 = t2 - (float)i02;
          float f3 = t3 - (float)i03;
          ushort4 p0 = tabl[(size_t)i00*64];
          ushort4 p1 = tabl[(size_t)i01*64];
          ushort4 p2 = tabl[(size_t)i02*64];
          ushort4 p3 = tabl[(size_t)i03*64];
          ushort2 x0 = xh2[(size_t)r0*64];
          ushort2 x1 = xh2[(size_t)r1*64];
          ushort2 x2 = xh2[(size_t)r2*64];
          ushort2 x3 = xh2[(size_t)r3*64];
          float aX, aY, dX, dY;
          aX=bf2f(p0.x); aY=bf2f(p0.y); dX=bf2f(p0.z)-aX; dY=bf2f(p0.w)-aY;
          ax = fmaf(bf2f(x0.x), fmaf(f0, dX, aX), ax);
          ay = fmaf(bf2f(x0.y), fmaf(f0, dY, aY), ay);
          aX=bf2f(p1.x); aY=bf2f(p1.y); dX=bf2f(p1.z)-aX; dY=bf2f(p1.w)-aY;
          ax = fmaf(bf2f(x1.x), fmaf(f1, dX, aX), ax);
          ay = fmaf(bf2f(x1.y), fmaf(f1, dY, aY), ay);
          aX=bf2f(p2.x); aY=bf2f(p2.y); dX=bf2f(p2.z)-aX; dY=bf2f(p2.w)-aY;
          ax = fmaf(bf2f(x2.x), fmaf(f2, dX, aX), ax);
          ay = fmaf(bf2f(x2.y), fmaf(f2, dY, aY), ay);
          aX=bf2f(p3.x); aY=bf2f(p3.y); dX=bf2f(p3.z)-aX; dY=bf2f(p3.w)-aY;
          ax = fmaf(bf2f(x3.x), fmaf(f3, dX, aX), ax);
          ay = fmaf(bf2f(x3.y), fmaf(f3, dY, aY), ay);
        }
        for (; j < cnt; ++j){
          int   r0 = __shfl(s_l, j, 64);
          float t0 = __shfl(t_l, j, 64);
          int i00 = (int)t0; if (i00 > 1023) i00 = 1023;
          float f0 = t0 - (float)i00;
          ushort4 p0 = tabl[(size_t)i00*64];
          ushort2 x0 = xh2[(size_t)r0*64];
          float aX=bf2f(p0.x), aY=bf2f(p0.y), dX=bf2f(p0.z)-aX, dY=bf2f(p0.w)-aY;
          ax = fmaf(bf2f(x0.x), fmaf(f0, dX, aX), ax);
          ay = fmaf(bf2f(x0.y), fmaf(f0, dY, aY), ay);
        }
      }
      *(float2*)((char*)Sa + swzf((wv*4+i)*512 + lane*8)) = make_float2(ax, ay);
    }
  }
  __syncthreads();

  // ===== phase 2 =====
  const int m = lane & 15, g = lane >> 4;
  const int colA = wv*32 + m;
  const int colB = colA + 16;
  const size_t wfo = (size_t)(wv*8*64 + lane)*8;
  const f32x4 vzero = {0.f,0.f,0.f,0.f};
  bf16x8 ah[4], al[4];
  f32x4 acc[2];

  // ---- stage A: t = ssp(agg @ W2 + b2) ----
  #pragma unroll
  for (int ks=0;ks<4;++ks){
    int lin = m*512 + (ks*32 + g*8)*4;
    split8(*(const float4*)((const char*)Sa + swzf(lin)),
           *(const float4*)((const char*)Sa + swzf(lin + 16)), ah[ks], al[ks]);
  }
  acc[0] = vzero; acc[1] = vzero;
  gemm_hl(w2p, wfo, ah, al, acc);
  {
    const float b20 = B2[colA], b21 = B2[colB];
    #pragma unroll
    for (int r=0;r<4;++r){
      const int row = g*4 + r;
      *(float*)((char*)St + swzf(row*512 + colA*4)) = ssp_f(acc[0][r] + b20);
      *(float*)((char*)St + swzf(row*512 + colB*4)) = ssp_f(acc[1][r] + b21);
    }
  }
  __syncthreads();

  // ---- stage B: h' = h + t @ WL + bl ----
  #pragma unroll
  for (int ks=0;ks<4;++ks){
    int lin = m*512 + (ks*32 + g*8)*4;
    split8(*(const float4*)((const char*)St + swzf(lin)),
           *(const float4*)((const char*)St + swzf(lin + 16)), ah[ks], al[ks]);
  }
  float hr0[4], hr1[4];
  #pragma unroll
  for (int r=0;r<4;++r){
    hr0[r] = Hio[(size_t)(m0 + g*4 + r)*HDIM + colA];
    hr1[r] = Hio[(size_t)(m0 + g*4 + r)*HDIM + colB];
  }
  acc[0] = vzero; acc[1] = vzero;
  gemm_hl(wlp, wfo, ah, al, acc);
  // Sa's last readers were the stage-A frag loads (pre-barrier) -> safe.
  {
    const float bl0 = BL[colA], bl1 = BL[colB];
    #pragma unroll
    for (int r=0;r<4;++r){
      const int row = g*4 + r;
      float v0 = hr0[r] + acc[0][r] + bl0;
      float v1 = hr1[r] + acc[1][r] + bl1;
      Hio[(size_t)(m0+row)*HDIM + colA] = v0;
      Hio[(size_t)(m0+row)*HDIM + colB] = v1;
      *(float*)((char*)Sa + swzf(row*512 + colA*4)) = v0;
      *(float*)((char*)Sa + swzf(row*512 + colB*4)) = v1;
    }
  }
  __syncthreads();

  if (LAST){
    // ---- fused output MLP: nodeval = ssp(h' @ ow1 + ob1) @ ow2 + ob2 ----
    for (int i=0;i<4;++i){
      const int row  = wv*4 + i;
      const int node = m0 + row;
      float acc1 = ob1[lane];
      #pragma unroll 4
      for (int k=0;k<HDIM;++k){
        float hv = *(const float*)((const char*)Sa + swzf(row*512 + k*4));
        acc1 = fmaf(hv, ow1[k*64 + lane], acc1);
      }
      float s = ssp_f(acc1) * ow2[lane];
      for (int off=32; off>0; off>>=1) s += __shfl_down(s, off, 64);
      if (lane == 0) nodeval[node] = s + ob2[0];
    }
    return;
  }

  // ---- stage C: xh_next(bf16) = h' @ W1n ----
  #pragma unroll
  for (int ks=0;ks<4;++ks){
    int lin = m*512 + (ks*32 + g*8)*4;
    split8(*(const float4*)((const char*)Sa + swzf(lin)),
           *(const float4*)((const char*)Sa + swzf(lin + 16)), ah[ks], al[ks]);
  }
  acc[0] = vzero; acc[1] = vzero;
  gemm_hl(w1p, wfo, ah, al, acc);
  #pragma unroll
  for (int r=0;r<4;++r){
    const int row = g*4 + r;
    xh_nxt[(size_t)(m0+row)*HDIM + colA] = f2bf(acc[0][r]);
    xh_nxt[(size_t)(m0+row)*HDIM + colB] = f2bf(acc[1][r]);
  }
}

// ---------------- graph readout ----------------
__global__ __launch_bounds__(256) void k_outB(const float* __restrict__ nodeval,
    const int* __restrict__ batch, float* __restrict__ out){
  __shared__ float sred[4];
  int g = blockIdx.x;
  int t = threadIdx.x;
  float s = 0.f;
  for (int n = t; n < N_NODES; n += 256)
    if (batch[n] == g) s += nodeval[n];
  for (int off=32; off>0; off>>=1) s += __shfl_down(s, off, 64);
  if ((t & 63) == 0) sred[t >> 6] = s;
  __syncthreads();
  if (t == 0){
    float tot = sred[0] + sred[1] + sred[2] + sred[3];
    out[g] = 1.0f/(1.0f + __expf(-tot));
  }
}

// ---------------- host ----------------
extern "C" void kernel_launch(void* const* d_in, const int* in_sizes, int n_in,
                              void* d_out, int out_size, void* d_ws, size_t ws_size,
                              hipStream_t stream){
  (void)in_sizes; (void)n_in; (void)out_size;
  const int*   z      = (const int*)  d_in[0];
  const float* pos    = (const float*)d_in[1];
  const int*   ei     = (const int*)  d_in[2];
  const int*   batch  = (const int*)  d_in[3];
  const float* emb    = (const float*)d_in[4];
  const float* mlp_w1 = (const float*)d_in[5];
  const float* mlp_b1 = (const float*)d_in[6];
  const float* mlp_w2 = (const float*)d_in[7];
  const float* mlp_b2 = (const float*)d_in[8];
  const float* cf_w1  = (const float*)d_in[9];
  const float* cf_w2  = (const float*)d_in[10];
  const float* cf_b2  = (const float*)d_in[11];
  const float* lin_w  = (const float*)d_in[12];
  const float* lin_b  = (const float*)d_in[13];
  const float* ow1    = (const float*)d_in[14];
  const float* ob1    = (const float*)d_in[15];
  const float* ow2    = (const float*)d_in[16];
  const float* ob2    = (const float*)d_in[17];

  char* wp = (char*)d_ws;
  size_t used = 0;
  auto alloc = [&](size_t bytes)->char*{
    char* p = wp + used;
    used += (bytes + 1023) & ~(size_t)1023;
    return p;
  };
  float*   tab     = (float*)alloc((size_t)NLAYER*TROWS*HDIM*4);
  ushort4* tabp    = (ushort4*)alloc((size_t)NLAYER*1024*64*8);
  float*   h       = (float*)alloc((size_t)N_NODES*HDIM*4);
  ushort*  xhb0    = (ushort*)alloc((size_t)N_NODES*HDIM*2);
  ushort*  xhb1    = (ushort*)alloc((size_t)N_NODES*HDIM*2);
  ushort*  wpk     = (ushort*)alloc((size_t)36*WPL*2);
  int*     rowptr  = (int*)  alloc((size_t)(N_NODES+1)*4);
  int*     cursor  = (int*)  alloc((size_t)N_NODES*4);
  int*     srcl    = (int*)  alloc((size_t)N_EDGES*4);
  float*   tl      = (float*)alloc((size_t)N_EDGES*4);
  float*   nodeval = (float*)alloc((size_t)N_NODES*4);
  if (used > ws_size) return;

  hipMemsetAsync(cursor, 0, (size_t)N_NODES*4, stream);

  k_setup1<<<K1_GRID, 256, 0, stream>>>(z, emb, h,
      mlp_w1, mlp_b1, mlp_w2, mlp_b2, tab, ei, cursor, cf_w2, lin_w, cf_w1, wpk);
  k_scan_pack<<<385, 1024, 0, stream>>>(cursor, rowptr, tab, tabp);
  k_fill_xh<<<2048, 256, 0, stream>>>(ei, pos, cursor, srcl, tl, h, cf_w1, (ushort4*)xhb0);

  for (int l=0; l<NLAYER; ++l){
    const ushort* w2p = wpk + (size_t)(2*l)*WPL;        // cf_w2[l]
    const ushort* wlp = wpk + (size_t)(2*(6+l))*WPL;    // lin_w[l]
    const ushort2* xcur = (const ushort2*)((l & 1) ? xhb1 : xhb0);
    ushort*        xnxt = (l & 1) ? xhb0 : xhb1;
    if (l < NLAYER-1){
      const ushort* w1p = wpk + (size_t)(2*(13+l))*WPL; // cf_w1[l+1]
      k_layer<false><<<N_NODES/16, 256, 0, stream>>>(rowptr, srcl, tl,
                 tabp + (size_t)l*1024*64, xcur,
                 w2p, cf_b2 + (size_t)l*HDIM, wlp, lin_b + (size_t)l*HDIM, h,
                 w1p, xnxt, nullptr, nullptr, nullptr, nullptr, nullptr);
    } else {
      k_layer<true><<<N_NODES/16, 256, 0, stream>>>(rowptr, srcl, tl,
                 tabp + (size_t)l*1024*64, xcur,
                 w2p, cf_b2 + (size_t)l*HDIM, wlp, lin_b + (size_t)l*HDIM, h,
                 nullptr, nullptr, ow1, ob1, ow2, ob2, nodeval);
    }
  }
  k_outB  <<<NGRAPH, 256, 0, stream>>>(nodeval, batch, (float*)d_out);
}

// Round 8
// 370.102 us; speedup vs baseline: 3.2365x; 1.0108x over previous
//
#include <hip/hip_runtime.h>
#include <math.h>

#define N_NODES 16384
#define N_EDGES 262144
#define HDIM    128
#define NG50    50
#define NLAYER  6
#define NGRAPH  16
#define TROWS   1025
#define RMAXF   4.34f
#define WPL     16384   // ushorts per packed weight plane (128*128)

__device__ __forceinline__ float ssp_f(float x){
  return (x > 20.0f ? x : log1pf(__expf(x))) - 0.6931471805599453f;
}
__device__ __forceinline__ void fma4(float4& c, float a, const float4 b){
  c.x = fmaf(a,b.x,c.x); c.y = fmaf(a,b.y,c.y); c.z = fmaf(a,b.z,c.z); c.w = fmaf(a,b.w,c.w);
}
// bf16 helpers (RNE)
__device__ __forceinline__ unsigned short f2bf(float x){
  unsigned u = __float_as_uint(x);
  u += 0x7FFF + ((u>>16)&1);
  return (unsigned short)(u>>16);
}
__device__ __forceinline__ float bf2f(unsigned short u){
  return __uint_as_float(((unsigned)u)<<16);
}
// wave-uniform broadcast into SGPRs (v_readlane -> scalar pipe addressing)
__device__ __forceinline__ unsigned rdlane_u(int v, int l){
  return (unsigned)__builtin_amdgcn_readlane(v, l);
}
__device__ __forceinline__ float rdlane_f(float v, int l){
  return __uint_as_float((unsigned)__builtin_amdgcn_readlane((int)__float_as_uint(v), l));
}

// MFMA fragment types
typedef __attribute__((ext_vector_type(8))) short bf16x8;
typedef __attribute__((ext_vector_type(4))) float f32x4;
// LDS XOR swizzle for fp32 [16][128] tiles (512 B rows): involution on 16B
// granules; route EVERY 16B half of a 32B fragment through swzf (R1 lesson).
__device__ __forceinline__ int swzf(int lin){ return lin ^ (((lin>>9)&7)<<4); }

// hi/lo bf16 split of 8 fp32 values (Dekker-style: lo = bf16(x - hi))
__device__ __forceinline__ void split8(const float4 v0, const float4 v1, bf16x8& hi, bf16x8& lo){
  float x[8] = {v0.x,v0.y,v0.z,v0.w,v1.x,v1.y,v1.z,v1.w};
  #pragma unroll
  for (int i=0;i<8;++i){
    unsigned short h = f2bf(x[i]);
    hi[i] = (short)h;
    lo[i] = (short)f2bf(x[i] - bf2f(h));
  }
}

// ================= K1: init_h || tab || hist || wpack =================
#define TAB_R   4
#define TAB_NB  257   // ceil(1025/4)
#define B_INIT  2048
#define B_TAB   1542  // NLAYER*TAB_NB
#define B_HIST  1024
#define B_WPACK 144
#define K1_GRID (B_INIT + B_TAB + B_HIST + B_WPACK)

__global__ __launch_bounds__(256) void k_setup1(
    const int* __restrict__ z, const float* __restrict__ emb, float* __restrict__ h,
    const float* __restrict__ w1, const float* __restrict__ b1,
    const float* __restrict__ w2, const float* __restrict__ b2, float* __restrict__ tab,
    const int* __restrict__ ei, int* __restrict__ cursor,
    const float* __restrict__ cf_w2, const float* __restrict__ lin_w,
    const float* __restrict__ cf_w1, ushort* __restrict__ wp)
{
  __shared__ float ea[TAB_R][52];
  __shared__ float sT[TAB_R][HDIM];
  __shared__ float part[2][TAB_R][HDIM];
  const int b = blockIdx.x;
  const int tid = threadIdx.x;

  if (b < B_INIT){
    int t = b*256 + tid;
    int n = t >> 5, q = t & 31;
    ((float4*)h)[t] = ((const float4*)emb)[(z[n]<<5) + q];
    return;
  }
  if (b < B_INIT + B_TAB){
    int bb = b - B_INIT;
    int l  = bb / TAB_NB;
    int i0 = (bb % TAB_NB) * TAB_R;
    int j    = tid & 127;
    int half = tid >> 7;
    const float* w1l = w1 + (size_t)l*NG50*HDIM;
    const float* w2l = w2 + (size_t)l*HDIM*HDIM;
    float* tabl = tab + (size_t)l*TROWS*HDIM;
    const float STEP = RMAXF/1024.0f;
    const float GS   = 10.0f/49.0f;
    const float GC   = -0.5f/(GS*GS);
    if (tid < TAB_R*NG50){
      int rr = tid / NG50, k = tid - rr*NG50;
      int ri = i0 + rr; if (ri > TROWS-1) ri = TROWS-1;
      float d = ri*STEP - k*GS;
      ea[rr][k] = __expf(GC*d*d);
    }
    __syncthreads();
    {
      float acc[TAB_R] = {0,0,0,0};
      int kb = half*25;
      for (int k=0;k<25;++k){
        float wv = w1l[(kb+k)*HDIM + j];
        #pragma unroll
        for (int r=0;r<TAB_R;++r) acc[r] = fmaf(ea[r][kb+k], wv, acc[r]);
      }
      #pragma unroll
      for (int r=0;r<TAB_R;++r) part[half][r][j] = acc[r];
    }
    __syncthreads();
    {
      float b1v = b1[(size_t)l*HDIM + j];
      #pragma unroll
      for (int rr=0;rr<2;++rr){
        int r = half*2 + rr;
        sT[r][j] = ssp_f(part[0][r][j] + part[1][r][j] + b1v);
      }
    }
    __syncthreads();
    {
      float o[TAB_R] = {0,0,0,0};
      int kb = half*64;
      #pragma unroll 4
      for (int k=0;k<64;++k){
        float wv = w2l[(kb+k)*HDIM + j];
        #pragma unroll
        for (int r=0;r<TAB_R;++r) o[r] = fmaf(sT[r][kb+k], wv, o[r]);
      }
      #pragma unroll
      for (int r=0;r<TAB_R;++r) part[half][r][j] = o[r];
    }
    __syncthreads();
    {
      float b2v = b2[(size_t)l*HDIM + j];
      #pragma unroll
      for (int rr=0;rr<2;++rr){
        int r = half*2 + rr;
        int ri = i0 + r;
        if (ri < TROWS){
          float rv = ri*STEP;
          float C = 0.5f*(cosf(rv*0.31415926535897931f) + 1.0f);
          tabl[(size_t)ri*HDIM + j] = (part[0][r][j] + part[1][r][j] + b2v)*C;
        }
      }
    }
    return;
  }
  if (b < B_INIT + B_TAB + B_HIST){
    int e = (b - (B_INIT + B_TAB))*256 + tid;
    if (e < N_EDGES) atomicAdd(&cursor[ei[N_EDGES + e]], 1);
    return;
  }
  {
    int bb  = b - (B_INIT + B_TAB + B_HIST);   // 0..143 = 18 mats x 8 parts
    int mat = bb >> 3;
    int s   = (bb & 7)*256 + tid;
    const float* M = (mat < 6)  ? cf_w2 + (size_t)mat*HDIM*HDIM
                   : (mat < 12) ? lin_w + (size_t)(mat-6)*HDIM*HDIM
                                : cf_w1 + (size_t)(mat-12)*HDIM*HDIM;
    int ct = s >> 8, ks = (s >> 6) & 3, l = s & 63;
    int col = ct*16 + (l & 15);
    int r0  = ks*32 + (l >> 4)*8;
    ushort oh[8], ol[8];
    #pragma unroll
    for (int i=0;i<8;++i){
      float w = M[(size_t)(r0+i)*HDIM + col];
      oh[i] = f2bf(w);
      ol[i] = f2bf(w - bf2f(oh[i]));
    }
    ushort* dh = wp + (size_t)(2*mat)*WPL + (size_t)s*8;
    ushort* dl = dh + WPL;
    *(ushort4*)(dh+0) = make_ushort4(oh[0],oh[1],oh[2],oh[3]);
    *(ushort4*)(dh+4) = make_ushort4(oh[4],oh[5],oh[6],oh[7]);
    *(ushort4*)(dl+0) = make_ushort4(ol[0],ol[1],ol[2],ol[3]);
    *(ushort4*)(dl+4) = make_ushort4(ol[4],ol[5],ol[6],ol[7]);
  }
}

// ================= K2: scan (block 0) || pack (blocks 1..384) =================
__global__ __launch_bounds__(1024) void k_scan_pack(int* __restrict__ cursor,
    int* __restrict__ rowptr, const float* __restrict__ tab, ushort4* __restrict__ tabp){
  __shared__ int sbuf[1024];
  int t = threadIdx.x;
  if (blockIdx.x == 0){
    int base = t*16;
    int d[16]; int s = 0;
    #pragma unroll
    for (int i=0;i<16;++i){ d[i] = cursor[base+i]; s += d[i]; }
    sbuf[t] = s; __syncthreads();
    for (int off=1; off<1024; off<<=1){
      int v = sbuf[t];
      int add = (t >= off) ? sbuf[t-off] : 0;
      __syncthreads();
      sbuf[t] = v + add;
      __syncthreads();
    }
    int run = (t==0) ? 0 : sbuf[t-1];
    #pragma unroll
    for (int i=0;i<16;++i){ rowptr[base+i] = run; cursor[base+i] = run; run += d[i]; }
    if (t==1023) rowptr[N_NODES] = run;
    return;
  }
  size_t tt = (size_t)(blockIdx.x-1)*1024 + t;   // 384*1024 = NLAYER*1024*64
  int lane = (int)(tt & 63);
  size_t row = tt >> 6;
  size_t l = row >> 10, i = row & 1023;
  const float* a = tab + (l*TROWS + i)*HDIM + lane*2;
  float2 av = *(const float2*)a;
  float2 bv = *(const float2*)(a + HDIM);
  ushort4 p;
  p.x = f2bf(av.x); p.y = f2bf(av.y); p.z = f2bf(bv.x); p.w = f2bf(bv.y);
  tabp[tt] = p;
}

// ================= K3: fill (blocks 0..1023) || gemm_xh (1024..2047) ==========
// fill now PRE-SPLITS the lerp: i = min((int)t,1023), f = t - i (bit-identical
// to what k_layer recomputed 6x/edge before), and packs (src<<10)|i in srcl.
#define FR 16
__global__ __launch_bounds__(256,4) void k_fill_xh(
    const int* __restrict__ ei, const float* __restrict__ pos,
    int* __restrict__ cursor, int* __restrict__ srcl, float* __restrict__ tl,
    const float* __restrict__ A, const float* __restrict__ B, ushort4* __restrict__ Cb)
{
  __shared__ float Bs[32*HDIM];
  const int tid = threadIdx.x;
  if (blockIdx.x < 1024){
    int e = blockIdx.x*256 + tid;
    if (e < N_EDGES){
      int a = ei[e];
      int c = ei[N_EDGES + e];
      float dx = pos[3*a+0] - pos[3*c+0];
      float dy = pos[3*a+1] - pos[3*c+1];
      float dz = pos[3*a+2] - pos[3*c+2];
      dx -= rintf(dx*0.2f)*5.0f;
      dy -= rintf(dy*0.2f)*5.0f;
      dz -= rintf(dz*0.2f)*5.0f;
      float r = sqrtf(fmaf(dx,dx,fmaf(dy,dy,dz*dz)));
      float t = r * (1024.0f/RMAXF);
      int ii = (int)t; if (ii > 1023) ii = 1023;
      float f = t - (float)ii;
      int slot = atomicAdd(&cursor[c], 1);
      srcl[slot] = (a << 10) | ii;
      tl[slot]   = f;
    }
    return;
  }
  // xh(bf16) = h @ cf_w1[0]
  int m0 = (blockIdx.x - 1024)*FR;
  int tc = tid & 31, tr = tid >> 5;
  int j0 = tc*4;
  int lr0 = tr*2, lr1 = tr*2+1;
  float4 acc0 = make_float4(0,0,0,0), acc1 = acc0;
  const float* A0 = A + (size_t)(m0 + lr0)*HDIM;
  const float* A1 = A + (size_t)(m0 + lr1)*HDIM;
  for (int kc=0; kc<HDIM; kc+=32){
    __syncthreads();
    {
      const float4* src = (const float4*)(B + kc*HDIM);
      float4* dst = (float4*)Bs;
      #pragma unroll
      for (int i=0;i<4;++i) dst[tid + i*256] = src[tid + i*256];
    }
    __syncthreads();
    #pragma unroll
    for (int kk=0; kk<32; kk+=4){
      float4 b0 = *(const float4*)(Bs + (kk+0)*HDIM + j0);
      float4 b1 = *(const float4*)(Bs + (kk+1)*HDIM + j0);
      float4 b2 = *(const float4*)(Bs + (kk+2)*HDIM + j0);
      float4 b3 = *(const float4*)(Bs + (kk+3)*HDIM + j0);
      float4 a0 = *(const float4*)(A0 + kc + kk);
      float4 a1 = *(const float4*)(A1 + kc + kk);
      fma4(acc0,a0.x,b0); fma4(acc0,a0.y,b1); fma4(acc0,a0.z,b2); fma4(acc0,a0.w,b3);
      fma4(acc1,a1.x,b0); fma4(acc1,a1.y,b1); fma4(acc1,a1.z,b2); fma4(acc1,a1.w,b3);
    }
  }
  ushort4 o;
  o.x=f2bf(acc0.x); o.y=f2bf(acc0.y); o.z=f2bf(acc0.z); o.w=f2bf(acc0.w);
  Cb[(size_t)(m0 + lr0)*32 + tc] = o;
  o.x=f2bf(acc1.x); o.y=f2bf(acc1.y); o.z=f2bf(acc1.z); o.w=f2bf(acc1.w);
  Cb[(size_t)(m0 + lr1)*32 + tc] = o;
}

// ================= per-layer: agg (LDS) -> 3x MFMA hi/lo stages ==============
// Gather: SCALARIZED. Per-edge (pk,f) broadcast via v_readlane into SGPRs ->
// row-base math on SALU, tab/xh loads as SGPR-base + fixed lane voffset.
// Removes the 2 ds_bpermute + cvt/clamp + 64-bit VALU addressing per edge
// (R7: VALUBusy 59%). Edge order and fma sequence identical -> bit-exact.
__device__ __forceinline__ void gemm_hl(const ushort* plane, size_t wfo,
    const bf16x8* ah, const bf16x8* al, f32x4* acc){
  #pragma unroll
  for (int ks=0;ks<4;++ks){
    #pragma unroll
    for (int c=0;c<2;++c){
      const ushort* p = plane + wfo + (size_t)(c*4+ks)*512;
      bf16x8 wh = *(const bf16x8*)p;
      bf16x8 wl = *(const bf16x8*)(p + WPL);
      acc[c] = __builtin_amdgcn_mfma_f32_16x16x32_bf16(ah[ks], wh, acc[c], 0,0,0);
      acc[c] = __builtin_amdgcn_mfma_f32_16x16x32_bf16(al[ks], wh, acc[c], 0,0,0);
      acc[c] = __builtin_amdgcn_mfma_f32_16x16x32_bf16(ah[ks], wl, acc[c], 0,0,0);
    }
  }
}
template<bool LAST>
__global__ __launch_bounds__(256,4) void k_layer(
    const int* __restrict__ rowptr, const int* __restrict__ srcl, const float* __restrict__ tl,
    const ushort4* __restrict__ tabp, const ushort2* __restrict__ xh_cur,
    const ushort* __restrict__ w2p, const float* __restrict__ B2,
    const ushort* __restrict__ wlp, const float* __restrict__ BL,
    float* __restrict__ Hio, const ushort* __restrict__ w1p, ushort* __restrict__ xh_nxt,
    const float* __restrict__ ow1, const float* __restrict__ ob1,
    const float* __restrict__ ow2, const float* __restrict__ ob2,
    float* __restrict__ nodeval)
{
  __shared__ alignas(16) float Sa[16*HDIM];   // 8 KB: agg, then h'
  __shared__ alignas(16) float St[16*HDIM];   // 8 KB: t
  const int tid  = threadIdx.x;
  const int wv   = tid >> 6, lane = tid & 63;
  const int m0   = blockIdx.x * 16;

  // ===== phase 1: aggregate 4 nodes per wave (scalarized 8-edge unroll) =====
  {
    for (int i=0;i<4;++i){
      int c = m0 + wv*4 + i;
      int beg = rowptr[c], end = rowptr[c+1];
      float ax = 0.f, ay = 0.f;
      for (int k0 = beg; k0 < end; k0 += 64){
        int rem = end - k0;
        int cnt = rem < 64 ? rem : 64;
        int   pk_l = 0; float f_l = 0.f;
        if (lane < cnt){ pk_l = srcl[k0+lane]; f_l = tl[k0+lane]; }
        int j = 0;
        for (; j+7 < cnt; j += 8){
          unsigned pk0 = rdlane_u(pk_l, j  ); float f0 = rdlane_f(f_l, j  );
          unsigned pk1 = rdlane_u(pk_l, j+1); float f1 = rdlane_f(f_l, j+1);
          unsigned pk2 = rdlane_u(pk_l, j+2); float f2 = rdlane_f(f_l, j+2);
          unsigned pk3 = rdlane_u(pk_l, j+3); float f3 = rdlane_f(f_l, j+3);
          unsigned pk4 = rdlane_u(pk_l, j+4); float f4 = rdlane_f(f_l, j+4);
          unsigned pk5 = rdlane_u(pk_l, j+5); float f5 = rdlane_f(f_l, j+5);
          unsigned pk6 = rdlane_u(pk_l, j+6); float f6 = rdlane_f(f_l, j+6);
          unsigned pk7 = rdlane_u(pk_l, j+7); float f7 = rdlane_f(f_l, j+7);
          ushort4 p0 = tabp[(pk0 & 1023u)*64u + (unsigned)lane];
          ushort4 p1 = tabp[(pk1 & 1023u)*64u + (unsigned)lane];
          ushort4 p2 = tabp[(pk2 & 1023u)*64u + (unsigned)lane];
          ushort4 p3 = tabp[(pk3 & 1023u)*64u + (unsigned)lane];
          ushort4 p4 = tabp[(pk4 & 1023u)*64u + (unsigned)lane];
          ushort4 p5 = tabp[(pk5 & 1023u)*64u + (unsigned)lane];
          ushort4 p6 = tabp[(pk6 & 1023u)*64u + (unsigned)lane];
          ushort4 p7 = tabp[(pk7 & 1023u)*64u + (unsigned)lane];
          ushort2 x0 = xh_cur[(pk0 >> 10)*64u + (unsigned)lane];
          ushort2 x1 = xh_cur[(pk1 >> 10)*64u + (unsigned)lane];
          ushort2 x2 = xh_cur[(pk2 >> 10)*64u + (unsigned)lane];
          ushort2 x3 = xh_cur[(pk3 >> 10)*64u + (unsigned)lane];
          ushort2 x4 = xh_cur[(pk4 >> 10)*64u + (unsigned)lane];
          ushort2 x5 = xh_cur[(pk5 >> 10)*64u + (unsigned)lane];
          ushort2 x6 = xh_cur[(pk6 >> 10)*64u + (unsigned)lane];
          ushort2 x7 = xh_cur[(pk7 >> 10)*64u + (unsigned)lane];
          float aX, aY, dX, dY;
          aX=bf2f(p0.x); aY=bf2f(p0.y); dX=bf2f(p0.z)-aX; dY=bf2f(p0.w)-aY;
          ax = fmaf(bf2f(x0.x), fmaf(f0, dX, aX), ax);
          ay = fmaf(bf2f(x0.y), fmaf(f0, dY, aY), ay);
          aX=bf2f(p1.x); aY=bf2f(p1.y); dX=bf2f(p1.z)-aX; dY=bf2f(p1.w)-aY;
          ax = fmaf(bf2f(x1.x), fmaf(f1, dX, aX), ax);
          ay = fmaf(bf2f(x1.y), fmaf(f1, dY, aY), ay);
          aX=bf2f(p2.x); aY=bf2f(p2.y); dX=bf2f(p2.z)-aX; dY=bf2f(p2.w)-aY;
          ax = fmaf(bf2f(x2.x), fmaf(f2, dX, aX), ax);
          ay = fmaf(bf2f(x2.y), fmaf(f2, dY, aY), ay);
          aX=bf2f(p3.x); aY=bf2f(p3.y); dX=bf2f(p3.z)-aX; dY=bf2f(p3.w)-aY;
          ax = fmaf(bf2f(x3.x), fmaf(f3, dX, aX), ax);
          ay = fmaf(bf2f(x3.y), fmaf(f3, dY, aY), ay);
          aX=bf2f(p4.x); aY=bf2f(p4.y); dX=bf2f(p4.z)-aX; dY=bf2f(p4.w)-aY;
          ax = fmaf(bf2f(x4.x), fmaf(f4, dX, aX), ax);
          ay = fmaf(bf2f(x4.y), fmaf(f4, dY, aY), ay);
          aX=bf2f(p5.x); aY=bf2f(p5.y); dX=bf2f(p5.z)-aX; dY=bf2f(p5.w)-aY;
          ax = fmaf(bf2f(x5.x), fmaf(f5, dX, aX), ax);
          ay = fmaf(bf2f(x5.y), fmaf(f5, dY, aY), ay);
          aX=bf2f(p6.x); aY=bf2f(p6.y); dX=bf2f(p6.z)-aX; dY=bf2f(p6.w)-aY;
          ax = fmaf(bf2f(x6.x), fmaf(f6, dX, aX), ax);
          ay = fmaf(bf2f(x6.y), fmaf(f6, dY, aY), ay);
          aX=bf2f(p7.x); aY=bf2f(p7.y); dX=bf2f(p7.z)-aX; dY=bf2f(p7.w)-aY;
          ax = fmaf(bf2f(x7.x), fmaf(f7, dX, aX), ax);
          ay = fmaf(bf2f(x7.y), fmaf(f7, dY, aY), ay);
        }
        for (; j+3 < cnt; j += 4){
          unsigned pk0 = rdlane_u(pk_l, j  ); float f0 = rdlane_f(f_l, j  );
          unsigned pk1 = rdlane_u(pk_l, j+1); float f1 = rdlane_f(f_l, j+1);
          unsigned pk2 = rdlane_u(pk_l, j+2); float f2 = rdlane_f(f_l, j+2);
          unsigned pk3 = rdlane_u(pk_l, j+3); float f3 = rdlane_f(f_l, j+3);
          ushort4 p0 = tabp[(pk0 & 1023u)*64u + (unsigned)lane];
          ushort4 p1 = tabp[(pk1 & 1023u)*64u + (unsigned)lane];
          ushort4 p2 = tabp[(pk2 & 1023u)*64u + (unsigned)lane];
          ushort4 p3 = tabp[(pk3 & 1023u)*64u + (unsigned)lane];
          ushort2 x0 = xh_cur[(pk0 >> 10)*64u + (unsigned)lane];
          ushort2 x1 = xh_cur[(pk1 >> 10)*64u + (unsigned)lane];
          ushort2 x2 = xh_cur[(pk2 >> 10)*64u + (unsigned)lane];
          ushort2 x3 = xh_cur[(pk3 >> 10)*64u + (unsigned)lane];
          float aX, aY, dX, dY;
          aX=bf2f(p0.x); aY=bf2f(p0.y); dX=bf2f(p0.z)-aX; dY=bf2f(p0.w)-aY;
          ax = fmaf(bf2f(x0.x), fmaf(f0, dX, aX), ax);
          ay = fmaf(bf2f(x0.y), fmaf(f0, dY, aY), ay);
          aX=bf2f(p1.x); aY=bf2f(p1.y); dX=bf2f(p1.z)-aX; dY=bf2f(p1.w)-aY;
          ax = fmaf(bf2f(x1.x), fmaf(f1, dX, aX), ax);
          ay = fmaf(bf2f(x1.y), fmaf(f1, dY, aY), ay);
          aX=bf2f(p2.x); aY=bf2f(p2.y); dX=bf2f(p2.z)-aX; dY=bf2f(p2.w)-aY;
          ax = fmaf(bf2f(x2.x), fmaf(f2, dX, aX), ax);
          ay = fmaf(bf2f(x2.y), fmaf(f2, dY, aY), ay);
          aX=bf2f(p3.x); aY=bf2f(p3.y); dX=bf2f(p3.z)-aX; dY=bf2f(p3.w)-aY;
          ax = fmaf(bf2f(x3.x), fmaf(f3, dX, aX), ax);
          ay = fmaf(bf2f(x3.y), fmaf(f3, dY, aY), ay);
        }
        for (; j < cnt; ++j){
          unsigned pk0 = rdlane_u(pk_l, j); float f0 = rdlane_f(f_l, j);
          ushort4 p0 = tabp[(pk0 & 1023u)*64u + (unsigned)lane];
          ushort2 x0 = xh_cur[(pk0 >> 10)*64u + (unsigned)lane];
          float aX=bf2f(p0.x), aY=bf2f(p0.y), dX=bf2f(p0.z)-aX, dY=bf2f(p0.w)-aY;
          ax = fmaf(bf2f(x0.x), fmaf(f0, dX, aX), ax);
          ay = fmaf(bf2f(x0.y), fmaf(f0, dY, aY), ay);
        }
      }
      *(float2*)((char*)Sa + swzf((wv*4+i)*512 + lane*8)) = make_float2(ax, ay);
    }
  }
  __syncthreads();

  // ===== phase 2 =====
  const int m = lane & 15, g = lane >> 4;
  const int colA = wv*32 + m;
  const int colB = colA + 16;
  const size_t wfo = (size_t)(wv*8*64 + lane)*8;
  const f32x4 vzero = {0.f,0.f,0.f,0.f};
  bf16x8 ah[4], al[4];
  f32x4 acc[2];

  // ---- stage A: t = ssp(agg @ W2 + b2) ----
  #pragma unroll
  for (int ks=0;ks<4;++ks){
    int lin = m*512 + (ks*32 + g*8)*4;
    split8(*(const float4*)((const char*)Sa + swzf(lin)),
           *(const float4*)((const char*)Sa + swzf(lin + 16)), ah[ks], al[ks]);
  }
  acc[0] = vzero; acc[1] = vzero;
  gemm_hl(w2p, wfo, ah, al, acc);
  {
    const float b20 = B2[colA], b21 = B2[colB];
    #pragma unroll
    for (int r=0;r<4;++r){
      const int row = g*4 + r;
      *(float*)((char*)St + swzf(row*512 + colA*4)) = ssp_f(acc[0][r] + b20);
      *(float*)((char*)St + swzf(row*512 + colB*4)) = ssp_f(acc[1][r] + b21);
    }
  }
  __syncthreads();

  // ---- stage B: h' = h + t @ WL + bl ----
  #pragma unroll
  for (int ks=0;ks<4;++ks){
    int lin = m*512 + (ks*32 + g*8)*4;
    split8(*(const float4*)((const char*)St + swzf(lin)),
           *(const float4*)((const char*)St + swzf(lin + 16)), ah[ks], al[ks]);
  }
  float hr0[4], hr1[4];
  #pragma unroll
  for (int r=0;r<4;++r){
    hr0[r] = Hio[(size_t)(m0 + g*4 + r)*HDIM + colA];
    hr1[r] = Hio[(size_t)(m0 + g*4 + r)*HDIM + colB];
  }
  acc[0] = vzero; acc[1] = vzero;
  gemm_hl(wlp, wfo, ah, al, acc);
  // Sa's last readers were the stage-A frag loads (pre-barrier) -> safe.
  {
    const float bl0 = BL[colA], bl1 = BL[colB];
    #pragma unroll
    for (int r=0;r<4;++r){
      const int row = g*4 + r;
      float v0 = hr0[r] + acc[0][r] + bl0;
      float v1 = hr1[r] + acc[1][r] + bl1;
      Hio[(size_t)(m0+row)*HDIM + colA] = v0;
      Hio[(size_t)(m0+row)*HDIM + colB] = v1;
      *(float*)((char*)Sa + swzf(row*512 + colA*4)) = v0;
      *(float*)((char*)Sa + swzf(row*512 + colB*4)) = v1;
    }
  }
  __syncthreads();

  if (LAST){
    // ---- fused output MLP: nodeval = ssp(h' @ ow1 + ob1) @ ow2 + ob2 ----
    for (int i=0;i<4;++i){
      const int row  = wv*4 + i;
      const int node = m0 + row;
      float acc1 = ob1[lane];
      #pragma unroll 4
      for (int k=0;k<HDIM;++k){
        float hv = *(const float*)((const char*)Sa + swzf(row*512 + k*4));
        acc1 = fmaf(hv, ow1[k*64 + lane], acc1);
      }
      float s = ssp_f(acc1) * ow2[lane];
      for (int off=32; off>0; off>>=1) s += __shfl_down(s, off, 64);
      if (lane == 0) nodeval[node] = s + ob2[0];
    }
    return;
  }

  // ---- stage C: xh_next(bf16) = h' @ W1n ----
  #pragma unroll
  for (int ks=0;ks<4;++ks){
    int lin = m*512 + (ks*32 + g*8)*4;
    split8(*(const float4*)((const char*)Sa + swzf(lin)),
           *(const float4*)((const char*)Sa + swzf(lin + 16)), ah[ks], al[ks]);
  }
  acc[0] = vzero; acc[1] = vzero;
  gemm_hl(w1p, wfo, ah, al, acc);
  #pragma unroll
  for (int r=0;r<4;++r){
    const int row = g*4 + r;
    xh_nxt[(size_t)(m0+row)*HDIM + colA] = f2bf(acc[0][r]);
    xh_nxt[(size_t)(m0+row)*HDIM + colB] = f2bf(acc[1][r]);
  }
}

// ---------------- graph readout ----------------
__global__ __launch_bounds__(256) void k_outB(const float* __restrict__ nodeval,
    const int* __restrict__ batch, float* __restrict__ out){
  __shared__ float sred[4];
  int g = blockIdx.x;
  int t = threadIdx.x;
  float s = 0.f;
  for (int n = t; n < N_NODES; n += 256)
    if (batch[n] == g) s += nodeval[n];
  for (int off=32; off>0; off>>=1) s += __shfl_down(s, off, 64);
  if ((t & 63) == 0) sred[t >> 6] = s;
  __syncthreads();
  if (t == 0){
    float tot = sred[0] + sred[1] + sred[2] + sred[3];
    out[g] = 1.0f/(1.0f + __expf(-tot));
  }
}

// ---------------- host ----------------
extern "C" void kernel_launch(void* const* d_in, const int* in_sizes, int n_in,
                              void* d_out, int out_size, void* d_ws, size_t ws_size,
                              hipStream_t stream){
  (void)in_sizes; (void)n_in; (void)out_size;
  const int*   z      = (const int*)  d_in[0];
  const float* pos    = (const float*)d_in[1];
  const int*   ei     = (const int*)  d_in[2];
  const int*   batch  = (const int*)  d_in[3];
  const float* emb    = (const float*)d_in[4];
  const float* mlp_w1 = (const float*)d_in[5];
  const float* mlp_b1 = (const float*)d_in[6];
  const float* mlp_w2 = (const float*)d_in[7];
  const float* mlp_b2 = (const float*)d_in[8];
  const float* cf_w1  = (const float*)d_in[9];
  const float* cf_w2  = (const float*)d_in[10];
  const float* cf_b2  = (const float*)d_in[11];
  const float* lin_w  = (const float*)d_in[12];
  const float* lin_b  = (const float*)d_in[13];
  const float* ow1    = (const float*)d_in[14];
  const float* ob1    = (const float*)d_in[15];
  const float* ow2    = (const float*)d_in[16];
  const float* ob2    = (const float*)d_in[17];

  char* wp = (char*)d_ws;
  size_t used = 0;
  auto alloc = [&](size_t bytes)->char*{
    char* p = wp + used;
    used += (bytes + 1023) & ~(size_t)1023;
    return p;
  };
  float*   tab     = (float*)alloc((size_t)NLAYER*TROWS*HDIM*4);
  ushort4* tabp    = (ushort4*)alloc((size_t)NLAYER*1024*64*8);
  float*   h       = (float*)alloc((size_t)N_NODES*HDIM*4);
  ushort*  xhb0    = (ushort*)alloc((size_t)N_NODES*HDIM*2);
  ushort*  xhb1    = (ushort*)alloc((size_t)N_NODES*HDIM*2);
  ushort*  wpk     = (ushort*)alloc((size_t)36*WPL*2);
  int*     rowptr  = (int*)  alloc((size_t)(N_NODES+1)*4);
  int*     cursor  = (int*)  alloc((size_t)N_NODES*4);
  int*     srcl    = (int*)  alloc((size_t)N_EDGES*4);
  float*   tl      = (float*)alloc((size_t)N_EDGES*4);
  float*   nodeval = (float*)alloc((size_t)N_NODES*4);
  if (used > ws_size) return;

  hipMemsetAsync(cursor, 0, (size_t)N_NODES*4, stream);

  k_setup1<<<K1_GRID, 256, 0, stream>>>(z, emb, h,
      mlp_w1, mlp_b1, mlp_w2, mlp_b2, tab, ei, cursor, cf_w2, lin_w, cf_w1, wpk);
  k_scan_pack<<<385, 1024, 0, stream>>>(cursor, rowptr, tab, tabp);
  k_fill_xh<<<2048, 256, 0, stream>>>(ei, pos, cursor, srcl, tl, h, cf_w1, (ushort4*)xhb0);

  for (int l=0; l<NLAYER; ++l){
    const ushort* w2p = wpk + (size_t)(2*l)*WPL;        // cf_w2[l]
    const ushort* wlp = wpk + (size_t)(2*(6+l))*WPL;    // lin_w[l]
    const ushort2* xcur = (const ushort2*)((l & 1) ? xhb1 : xhb0);
    ushort*        xnxt = (l & 1) ? xhb0 : xhb1;
    if (l < NLAYER-1){
      const ushort* w1p = wpk + (size_t)(2*(13+l))*WPL; // cf_w1[l+1]
      k_layer<false><<<N_NODES/16, 256, 0, stream>>>(rowptr, srcl, tl,
                 tabp + (size_t)l*1024*64, xcur,
                 w2p, cf_b2 + (size_t)l*HDIM, wlp, lin_b + (size_t)l*HDIM, h,
                 w1p, xnxt, nullptr, nullptr, nullptr, nullptr, nullptr);
    } else {
      k_layer<true><<<N_NODES/16, 256, 0, stream>>>(rowptr, srcl, tl,
                 tabp + (size_t)l*1024*64, xcur,
                 w2p, cf_b2 + (size_t)l*HDIM, wlp, lin_b + (size_t)l*HDIM, h,
                 nullptr, nullptr, ow1, ob1, ow2, ob2, nodeval);
    }
  }
  k_outB  <<<NGRAPH, 256, 0, stream>>>(nodeval, batch, (float*)d_out);
}